// Round 14
// baseline (225.237 us; speedup 1.0000x reference)
//
#include <hip/hip_runtime.h>
#include <hip/hip_bf16.h>
#include <stdint.h>

// B=2, T=4096, D=1024, H=16, HS=64. Pipeline:
// fused cvt -> GEMM qkv (8-phase counted-vmcnt 128x256; V TRANSPOSED [bh][e][t])
// -> flash attn (32x32 swapped MFMA, in-reg softmax, MFMA-ones rowsum, cvt_pk+
// permlane32_swap, defer-rescale, dbuf swizzled K/V) -> GEMM out (8-phase).

typedef __bf16 bf16x8 __attribute__((ext_vector_type(8)));
typedef float f32x4 __attribute__((ext_vector_type(4)));
typedef float f32x16 __attribute__((ext_vector_type(16)));
typedef __attribute__((address_space(1))) void gvoid_t;
typedef __attribute__((address_space(3))) void lvoid_t;

using hbf = __hip_bfloat16;

#define QSCALE (0.125f * 1.44269504088896f)  // 1/sqrt(HS) * log2(e)

static __device__ __forceinline__ void gload_lds16(const void* g, void* l) {
  __builtin_amdgcn_global_load_lds((gvoid_t*)g, (lvoid_t*)l, 16, 0, 0);
}

static __device__ __forceinline__ uint16_t b2u(float x) {
  hbf h = __float2bfloat16(x);
  return *reinterpret_cast<uint16_t*>(&h);
}

static __device__ __forceinline__ uint32_t cvtpk(float lo, float hi) {
  uint32_t r;
  asm("v_cvt_pk_bf16_f32 %0, %1, %2" : "=v"(r) : "v"(lo), "v"(hi));
  return r;
}

// v_permlane32_swap_b32: newX = {X.lo31 | Y.lo31->hi}, newY = {X.hi31->lo | Y.hi31}
static __device__ __forceinline__ void pl32swap(uint32_t& x, uint32_t& y) {
  asm volatile("v_permlane32_swap_b32 %0, %1" : "+v"(x), "+v"(y));
}

static __device__ __forceinline__ float max3f(float a, float b, float c) {
  return fmaxf(fmaxf(a, b), c);  // fuses to v_max3_f32
}

// ---------------- fused converters ----------------

__global__ void k_cvt_all(const float* __restrict__ x,
                          const float* __restrict__ Wq, const float* __restrict__ Wk,
                          const float* __restrict__ Wv,
                          const float* __restrict__ bq, const float* __restrict__ bk,
                          const float* __restrict__ bv,
                          const float* __restrict__ Wp,
                          hbf* __restrict__ xb, hbf* __restrict__ Wt,
                          hbf* __restrict__ Wpt, float* __restrict__ biasc) {
  const int b = blockIdx.x, tid = threadIdx.x;
  if (b < 8192) {
    int i = (b * 256 + tid) * 4;
    float4 v = *reinterpret_cast<const float4*>(x + i);
    hbf h[4] = {__float2bfloat16(v.x), __float2bfloat16(v.y),
                __float2bfloat16(v.z), __float2bfloat16(v.w)};
    *reinterpret_cast<ushort4*>(xb + i) = *reinterpret_cast<ushort4*>(h);
  } else if (b < 20480) {
    int idx = (b - 8192) * 256 + tid;   // 3072*1024
    int d = idx & 1023, r = idx >> 10;
    int m = r >> 10, rem = r & 1023;
    int h = rem >> 6, e = rem & 63;
    const float* W = (m == 0) ? Wq : (m == 1) ? Wk : Wv;
    float v = W[(h << 10 | d) * 64 + e];
    if (m == 0) v *= QSCALE;
    Wt[idx] = __float2bfloat16(v);
  } else if (b < 24576) {
    int idx = (b - 20480) * 256 + tid;  // 1024*1024
    int o = idx >> 10, d = idx & 1023;
    Wpt[idx] = __float2bfloat16(Wp[(d << 10) + o]);
  } else {
    int r = (b - 24576) * 256 + tid;    // 0..3071
    int m = r >> 10, rem = r & 1023;
    const float* bsrc = (m == 0) ? bq : (m == 1) ? bk : bv;
    float v = bsrc[rem];
    if (m == 0) v *= QSCALE;
    biasc[r] = v;
  }
}

// ---------------- QKV projection GEMM (8-phase, R12-verified) ----------------

__global__ __launch_bounds__(512) void k_gemm_qkv(
    const hbf* __restrict__ A, const hbf* __restrict__ Bw,
    const float* __restrict__ biasc, hbf* __restrict__ qkv) {
  __shared__ __align__(16) hbf sA[2][128 * 64];
  __shared__ __align__(16) hbf sB[2][256 * 64];
  const int tid = threadIdx.x;
  const int lane = tid & 63, w = tid >> 6;
  const int wm = w >> 2, wn = w & 3;
  const int g = lane >> 4, cl = lane & 15;
  const int m0 = blockIdx.x * 128, n0 = blockIdx.y * 256;
  const int sr = tid >> 3, sc = tid & 7;

  const f32x4 fz = {0.f, 0.f, 0.f, 0.f};
  f32x4 acc[4][4];
#pragma unroll
  for (int a = 0; a < 4; ++a)
#pragma unroll
    for (int b = 0; b < 4; ++b) acc[a][b] = fz;

#pragma unroll
  for (int kt = 0; kt < 2; ++kt) {
#pragma unroll
    for (int s = 0; s < 2; ++s) {
      const int row = s * 64 + sr;
      gload_lds16(A + (size_t)(m0 + row) * 1024 + kt * 64 + ((sc ^ (row & 7)) * 8),
                  &sA[kt][s * 4096 + tid * 8]);
    }
#pragma unroll
    for (int s = 0; s < 4; ++s) {
      const int row = s * 64 + sr;
      gload_lds16(Bw + (size_t)(n0 + row) * 1024 + kt * 64 + ((sc ^ (row & 7)) * 8),
                  &sB[kt][s * 4096 + tid * 8]);
    }
  }
  asm volatile("s_waitcnt vmcnt(6)" ::: "memory");
  __builtin_amdgcn_s_barrier();

  for (int kt = 0; kt < 16; ++kt) {
    const int bi = kt & 1;
    const bool st = (kt + 2) < 16;

    bf16x8 af[4][2], bf[4][2];
#pragma unroll
    for (int rt = 0; rt < 4; ++rt)
#pragma unroll
      for (int ks = 0; ks < 2; ++ks)
        af[rt][ks] = *reinterpret_cast<const bf16x8*>(
            &sA[bi][(wm * 64 + rt * 16 + cl) * 64 + (((ks * 4 + g) ^ (cl & 7)) * 8)]);
#pragma unroll
    for (int ct = 0; ct < 4; ++ct)
#pragma unroll
      for (int ks = 0; ks < 2; ++ks)
        bf[ct][ks] = *reinterpret_cast<const bf16x8*>(
            &sB[bi][(wn * 64 + ct * 16 + cl) * 64 + (((ks * 4 + g) ^ (cl & 7)) * 8)]);
    __builtin_amdgcn_s_barrier();
    asm volatile("s_waitcnt lgkmcnt(0)" ::: "memory");
    __builtin_amdgcn_sched_barrier(0);
    __builtin_amdgcn_s_setprio(1);
#pragma unroll
    for (int rt = 0; rt < 4; ++rt)
#pragma unroll
      for (int ks = 0; ks < 2; ++ks)
        acc[rt][0] = __builtin_amdgcn_mfma_f32_16x16x32_bf16(af[rt][ks], bf[0][ks], acc[rt][0], 0, 0, 0);
    __builtin_amdgcn_s_setprio(0);
    __builtin_amdgcn_s_barrier();

#pragma unroll
    for (int q = 1; q < 4; ++q) {
      if (st) {
        if (q == 1) {
#pragma unroll
          for (int s = 0; s < 2; ++s) {
            const int row = s * 64 + sr;
            gload_lds16(A + (size_t)(m0 + row) * 1024 + (kt + 2) * 64 + ((sc ^ (row & 7)) * 8),
                        &sA[bi][s * 4096 + tid * 8]);
          }
        } else {
#pragma unroll
          for (int s2 = 0; s2 < 2; ++s2) {
            const int s = (q - 2) * 2 + s2;
            const int row = s * 64 + sr;
            gload_lds16(Bw + (size_t)(n0 + row) * 1024 + (kt + 2) * 64 + ((sc ^ (row & 7)) * 8),
                        &sB[bi][s * 4096 + tid * 8]);
          }
        }
      }
      __builtin_amdgcn_s_setprio(1);
#pragma unroll
      for (int rt = 0; rt < 4; ++rt)
#pragma unroll
        for (int ks = 0; ks < 2; ++ks)
          acc[rt][q] = __builtin_amdgcn_mfma_f32_16x16x32_bf16(af[rt][ks], bf[q][ks], acc[rt][q], 0, 0, 0);
      __builtin_amdgcn_s_setprio(0);
      if (q == 3) {
        if (st) asm volatile("s_waitcnt vmcnt(6)" ::: "memory");
        else    asm volatile("s_waitcnt vmcnt(0)" ::: "memory");
      }
      __builtin_amdgcn_s_barrier();
    }
  }

#pragma unroll
  for (int rt = 0; rt < 4; ++rt)
#pragma unroll
    for (int ct = 0; ct < 4; ++ct) {
      const int colg = n0 + wn * 64 + ct * 16 + cl;
      const int mi = colg >> 10, rem = colg & 1023;
      const int h = rem >> 6, e = rem & 63;
      const float bi_ = biasc[colg];
      if (mi == 2) {
        const int t0 = m0 + wm * 64 + rt * 16 + g * 4;
        const int b = t0 >> 12, t = t0 & 4095;
        ushort4 o;
        o.x = b2u(acc[rt][ct][0] + bi_);
        o.y = b2u(acc[rt][ct][1] + bi_);
        o.z = b2u(acc[rt][ct][2] + bi_);
        o.w = b2u(acc[rt][ct][3] + bi_);
        *reinterpret_cast<ushort4*>(
            qkv + (size_t)64 * 262144 + (size_t)(b * 16 + h) * 262144 + (size_t)e * 4096 + t) = o;
      } else {
#pragma unroll
        for (int i = 0; i < 4; ++i) {
          const int rowg = m0 + wm * 64 + rt * 16 + g * 4 + i;
          const int b = rowg >> 12, t = rowg & 4095;
          qkv[(((size_t)mi * 32 + b * 16 + h) * 4096 + t) * 64 + e] =
              __float2bfloat16(acc[rt][ct][i] + bi_);
        }
      }
    }
}

// ---------------- flash attention ----------------
// R13 structure + MFMA-ones rowsum: accSum = sum_kb mfma(ones, P_kb) gives
// every lane its q-column's full 64-kv P-sum in accSum[0] (no VALU adds, no
// shfl); rescale touches accSum[0] only; epilogue divides by accSum[0].

__global__ __launch_bounds__(256) void k_flash(
    const hbf* __restrict__ qkv, hbf* __restrict__ attn) {
  __shared__ __align__(16) __bf16 sK[2][64 * 64];
  __shared__ __align__(16) __bf16 sV[2][64 * 64];
  const int tid = threadIdx.x, lane = tid & 63, wq = tid >> 6;
  const int h = lane >> 5, r31 = lane & 31;
  const int bh = blockIdx.x;
  const int qtb = (int)gridDim.y - 1 - (int)blockIdx.y;  // 0..31
  const int q0 = qtb * 128;
  const int ntile = 2 * qtb + 2;
  const hbf* Q  = qkv + (size_t)bh * 262144;
  const hbf* Kp = qkv + (size_t)(32 + bh) * 262144;
  const hbf* Vp = qkv + (size_t)(64 + bh) * 262144;  // [e=64][t=4096]
  const float NEG_INF = -__builtin_inff();

  const int koff = (wq * 16 + (lane >> 3)) * 64 + (((lane & 7) ^ (lane >> 3)) * 8);
  const int voff = (wq * 16 + (lane >> 3)) * 4096 + (((lane & 7) ^ (lane >> 3)) * 8);

  const int qrow = q0 + wq * 32 + r31;
  bf16x8 aq[4];
#pragma unroll
  for (int ks = 0; ks < 4; ++ks)
    aq[ks] = *reinterpret_cast<const bf16x8*>(Q + (size_t)qrow * 64 + ks * 16 + h * 8);

  union { uint32_t u[4]; bf16x8 v; } onesu;
  onesu.u[0] = onesu.u[1] = onesu.u[2] = onesu.u[3] = 0x3F803F80u;  // bf16 1.0 x8
  const bf16x8 vones = onesu.v;

  f32x16 accO[2], accSum;
#pragma unroll
  for (int et = 0; et < 2; ++et)
#pragma unroll
    for (int i = 0; i < 16; ++i) accO[et][i] = 0.f;
#pragma unroll
  for (int i = 0; i < 16; ++i) accSum[i] = 0.f;
  float mrow = NEG_INF;

  gload_lds16(Kp + koff,         &sK[0][wq * 1024]);
  gload_lds16(Kp + koff + 512,   &sK[0][wq * 1024 + 512]);
  gload_lds16(Vp + voff,         &sV[0][wq * 1024]);
  gload_lds16(Vp + voff + 32768, &sV[0][wq * 1024 + 512]);
  __syncthreads();

  const int qmaxw = q0 + wq * 32 + 31;
  int buf = 0;
  for (int jt = 0; jt < ntile; ++jt) {
    if (jt < ntile - 1) {
      const hbf* Kg = Kp + (size_t)(jt + 1) * 4096;
      gload_lds16(Kg + koff,       &sK[buf ^ 1][wq * 1024]);
      gload_lds16(Kg + koff + 512, &sK[buf ^ 1][wq * 1024 + 512]);
      const hbf* Vg = Vp + (jt + 1) * 64;
      gload_lds16(Vg + voff,         &sV[buf ^ 1][wq * 1024]);
      gload_lds16(Vg + voff + 32768, &sV[buf ^ 1][wq * 1024 + 512]);
    }

    if (64 * jt <= qmaxw) {
      const __bf16* sKb = sK[buf];
      const __bf16* sVb = sV[buf];

      f32x16 accS[2];
      __builtin_amdgcn_s_setprio(1);
#pragma unroll
      for (int t = 0; t < 2; ++t) {
        f32x16 s;
#pragma unroll
        for (int i = 0; i < 16; ++i) s[i] = 0.f;
#pragma unroll
        for (int ks = 0; ks < 4; ++ks) {
          bf16x8 ak = *reinterpret_cast<const bf16x8*>(
              sKb + (t * 32 + r31) * 64 + (((2 * ks + h) ^ (r31 & 7)) * 8));
          s = __builtin_amdgcn_mfma_f32_32x32x16_bf16(ak, aq[ks], s, 0, 0, 0);
        }
        accS[t] = s;
      }
      __builtin_amdgcn_s_setprio(0);

      if (64 * jt + 63 > q0 + wq * 32) {
#pragma unroll
        for (int t = 0; t < 2; ++t)
#pragma unroll
          for (int i = 0; i < 16; ++i) {
            const int kvg = 64 * jt + 32 * t + (i & 3) + 8 * (i >> 2) + 4 * h;
            if (kvg > qrow) accS[t][i] = NEG_INF;
          }
      }

      float g0 = max3f(accS[0][0], accS[0][1], accS[0][2]);
      float g1 = max3f(accS[0][3], accS[0][4], accS[0][5]);
      float g2 = max3f(accS[0][6], accS[0][7], accS[0][8]);
      float g3 = max3f(accS[0][9], accS[0][10], accS[0][11]);
      float g4 = max3f(accS[0][12], accS[0][13], accS[0][14]);
      float g5 = max3f(accS[0][15], accS[1][0], accS[1][1]);
      float g6 = max3f(accS[1][2], accS[1][3], accS[1][4]);
      float g7 = max3f(accS[1][5], accS[1][6], accS[1][7]);
      float g8 = max3f(accS[1][8], accS[1][9], accS[1][10]);
      float g9 = max3f(accS[1][11], accS[1][12], accS[1][13]);
      float gA = fmaxf(accS[1][14], accS[1][15]);
      float h0 = max3f(g0, g1, g2);
      float h1 = max3f(g3, g4, g5);
      float h2 = max3f(g6, g7, g8);
      float h3 = fmaxf(g9, gA);
      float pmax = fmaxf(max3f(h0, h1, h2), h3);
      pmax = fmaxf(pmax, __shfl_xor(pmax, 32));

      if (!__all(pmax - mrow <= 8.f)) {  // defer-rescale (T13)
        const float mn = fmaxf(mrow, pmax);
        const float corr = __builtin_amdgcn_exp2f(mrow - mn);
        mrow = mn;
        accSum[0] *= corr;   // only element 0 is ever read
#pragma unroll
        for (int et = 0; et < 2; ++et)
#pragma unroll
          for (int i = 0; i < 16; ++i) accO[et][i] *= corr;
      }

#pragma unroll
      for (int t = 0; t < 2; ++t)
#pragma unroll
        for (int i = 0; i < 16; ++i)
          accS[t][i] = __builtin_amdgcn_exp2f(accS[t][i] - mrow);

      uint32_t d0[2][4], d1[2][4];
#pragma unroll
      for (int t = 0; t < 2; ++t)
#pragma unroll
        for (int r4 = 0; r4 < 4; ++r4) {
          d0[t][r4] = cvtpk(accS[t][4 * r4 + 0], accS[t][4 * r4 + 1]);
          d1[t][r4] = cvtpk(accS[t][4 * r4 + 2], accS[t][4 * r4 + 3]);
        }

#pragma unroll
      for (int kb = 0; kb < 4; ++kb) {
        const int t = kb >> 1, ra = 2 * (kb & 1), rb = ra + 1;
        uint32_t x0 = d0[t][ra], y0 = d0[t][rb];
        uint32_t x1 = d1[t][ra], y1 = d1[t][rb];
        pl32swap(x0, y0);
        pl32swap(x1, y1);
        union { uint32_t u[4]; bf16x8 v; } bP;
        bP.u[0] = x0; bP.u[1] = x1; bP.u[2] = y0; bP.u[3] = y1;
        __builtin_amdgcn_s_setprio(1);
#pragma unroll
        for (int et = 0; et < 2; ++et) {
          bf16x8 av = *reinterpret_cast<const bf16x8*>(
              sVb + (et * 32 + r31) * 64 + (((2 * kb + h) ^ (r31 & 7)) * 8));
          accO[et] = __builtin_amdgcn_mfma_f32_32x32x16_bf16(av, bP.v, accO[et], 0, 0, 0);
        }
        // rowsum on the matrix pipe: every lane accumulates its column's P-sum
        accSum = __builtin_amdgcn_mfma_f32_32x32x16_bf16(vones, bP.v, accSum, 0, 0, 0);
        __builtin_amdgcn_s_setprio(0);
      }
    }

    __syncthreads();
    buf ^= 1;
  }

  const float inv = 1.0f / accSum[0];
  hbf* arow = attn + ((size_t)(bh >> 4) * 4096 + qrow) * 1024 + (bh & 15) * 64;
#pragma unroll
  for (int et = 0; et < 2; ++et)
#pragma unroll
    for (int r4 = 0; r4 < 4; ++r4) {
      const int e0 = et * 32 + 8 * r4 + 4 * h;
      ushort4 o;
      o.x = b2u(accO[et][4 * r4 + 0] * inv);
      o.y = b2u(accO[et][4 * r4 + 1] * inv);
      o.z = b2u(accO[et][4 * r4 + 2] * inv);
      o.w = b2u(accO[et][4 * r4 + 3] * inv);
      *reinterpret_cast<ushort4*>(arow + e0) = o;
    }
}

// ---------------- output projection GEMM (8-phase 128x256, fp32 out) ----------------

__global__ __launch_bounds__(512) void k_gemm_out(
    const hbf* __restrict__ A, const hbf* __restrict__ Bw,
    const float* __restrict__ bp, float* __restrict__ out) {
  __shared__ __align__(16) hbf sA[2][128 * 64];
  __shared__ __align__(16) hbf sB[2][256 * 64];
  const int tid = threadIdx.x;
  const int lane = tid & 63, w = tid >> 6;
  const int wm = w >> 2, wn = w & 3;
  const int g = lane >> 4, cl = lane & 15;
  const int m0 = blockIdx.x * 128, n0 = blockIdx.y * 256;
  const int sr = tid >> 3, sc = tid & 7;

  const f32x4 fz = {0.f, 0.f, 0.f, 0.f};
  f32x4 acc[4][4];
#pragma unroll
  for (int a = 0; a < 4; ++a)
#pragma unroll
    for (int b = 0; b < 4; ++b) acc[a][b] = fz;

#pragma unroll
  for (int kt = 0; kt < 2; ++kt) {
#pragma unroll
    for (int s = 0; s < 2; ++s) {
      const int row = s * 64 + sr;
      gload_lds16(A + (size_t)(m0 + row) * 1024 + kt * 64 + ((sc ^ (row & 7)) * 8),
                  &sA[kt][s * 4096 + tid * 8]);
    }
#pragma unroll
    for (int s = 0; s < 4; ++s) {
      const int row = s * 64 + sr;
      gload_lds16(Bw + (size_t)(n0 + row) * 1024 + kt * 64 + ((sc ^ (row & 7)) * 8),
                  &sB[kt][s * 4096 + tid * 8]);
    }
  }
  asm volatile("s_waitcnt vmcnt(6)" ::: "memory");
  __builtin_amdgcn_s_barrier();

  for (int kt = 0; kt < 16; ++kt) {
    const int bi = kt & 1;
    const bool st = (kt + 2) < 16;

    bf16x8 af[4][2], bf[4][2];
#pragma unroll
    for (int rt = 0; rt < 4; ++rt)
#pragma unroll
      for (int ks = 0; ks < 2; ++ks)
        af[rt][ks] = *reinterpret_cast<const bf16x8*>(
            &sA[bi][(wm * 64 + rt * 16 + cl) * 64 + (((ks * 4 + g) ^ (cl & 7)) * 8)]);
#pragma unroll
    for (int ct = 0; ct < 4; ++ct)
#pragma unroll
      for (int ks = 0; ks < 2; ++ks)
        bf[ct][ks] = *reinterpret_cast<const bf16x8*>(
            &sB[bi][(wn * 64 + ct * 16 + cl) * 64 + (((ks * 4 + g) ^ (cl & 7)) * 8)]);
    __builtin_amdgcn_s_barrier();
    asm volatile("s_waitcnt lgkmcnt(0)" ::: "memory");
    __builtin_amdgcn_sched_barrier(0);
    __builtin_amdgcn_s_setprio(1);
#pragma unroll
    for (int rt = 0; rt < 4; ++rt)
#pragma unroll
      for (int ks = 0; ks < 2; ++ks)
        acc[rt][0] = __builtin_amdgcn_mfma_f32_16x16x32_bf16(af[rt][ks], bf[0][ks], acc[rt][0], 0, 0, 0);
    __builtin_amdgcn_s_setprio(0);
    __builtin_amdgcn_s_barrier();

#pragma unroll
    for (int q = 1; q < 4; ++q) {
      if (st) {
        if (q == 1) {
#pragma unroll
          for (int s = 0; s < 2; ++s) {
            const int row = s * 64 + sr;
            gload_lds16(A + (size_t)(m0 + row) * 1024 + (kt + 2) * 64 + ((sc ^ (row & 7)) * 8),
                        &sA[bi][s * 4096 + tid * 8]);
          }
        } else {
#pragma unroll
          for (int s2 = 0; s2 < 2; ++s2) {
            const int s = (q - 2) * 2 + s2;
            const int row = s * 64 + sr;
            gload_lds16(Bw + (size_t)(n0 + row) * 1024 + (kt + 2) * 64 + ((sc ^ (row & 7)) * 8),
                        &sB[bi][s * 4096 + tid * 8]);
          }
        }
      }
      __builtin_amdgcn_s_setprio(1);
#pragma unroll
      for (int rt = 0; rt < 4; ++rt)
#pragma unroll
        for (int ks = 0; ks < 2; ++ks)
          acc[rt][q] = __builtin_amdgcn_mfma_f32_16x16x32_bf16(af[rt][ks], bf[q][ks], acc[rt][q], 0, 0, 0);
      __builtin_amdgcn_s_setprio(0);
      if (q == 3) {
        if (st) asm volatile("s_waitcnt vmcnt(6)" ::: "memory");
        else    asm volatile("s_waitcnt vmcnt(0)" ::: "memory");
      }
      __builtin_amdgcn_s_barrier();
    }
  }

#pragma unroll
  for (int rt = 0; rt < 4; ++rt)
#pragma unroll
    for (int ct = 0; ct < 4; ++ct) {
      const int colg = n0 + wn * 64 + ct * 16 + cl;
      const float bi_ = bp[colg];
#pragma unroll
      for (int i = 0; i < 4; ++i) {
        const int rowg = m0 + wm * 64 + rt * 16 + g * 4 + i;
        out[(size_t)rowg * 1024 + colg] = acc[rt][ct][i] + bi_;
      }
    }
}

// ---------------- launcher ----------------

extern "C" void kernel_launch(void* const* d_in, const int* in_sizes, int n_in,
                              void* d_out, int out_size, void* d_ws, size_t ws_size,
                              hipStream_t stream) {
  const float* x  = (const float*)d_in[0];
  const float* Wq = (const float*)d_in[1];
  const float* Wk = (const float*)d_in[2];
  const float* Wv = (const float*)d_in[3];
  const float* bq = (const float*)d_in[4];
  const float* bk = (const float*)d_in[5];
  const float* bv = (const float*)d_in[6];
  const float* Wp = (const float*)d_in[7];
  const float* bp = (const float*)d_in[8];
  float* out = (float*)d_out;

  char* ws = (char*)d_ws;
  hbf*   xb    = (hbf*)ws;                                   // 16 MiB (reused as attn_out)
  hbf*   Wt    = (hbf*)(ws + 16777216);                      // 6 MiB
  hbf*   Wpt   = (hbf*)(ws + 16777216 + 6291456);            // 2 MiB
  float* biasc = (float*)(ws + 16777216 + 6291456 + 2097152);// 12 KiB (+pad)
  hbf*   qkv   = (hbf*)(ws + 16777216 + 6291456 + 2097152 + 16384); // 48 MiB
  hbf*   attn  = xb;

  k_cvt_all<<<24588, 256, 0, stream>>>(x, Wq, Wk, Wv, bq, bk, bv, Wp,
                                       xb, Wt, Wpt, biasc);

  dim3 g1(64, 12); k_gemm_qkv<<<g1, 512, 0, stream>>>(xb, Wt, biasc, qkv);
  dim3 g2(32, 32); k_flash   <<<g2, 256, 0, stream>>>(qkv, attn);
  dim3 g3(64, 4);  k_gemm_out<<<g3, 512, 0, stream>>>(attn, Wpt, bp, out);
}

// Round 16
// 205.903 us; speedup vs baseline: 1.0939x; 1.0939x over previous
//
#include <hip/hip_runtime.h>
#include <hip/hip_bf16.h>
#include <stdint.h>

// B=2, T=4096, D=1024, H=16, HS=64. Pipeline:
// cvt (x+bias coalesced; Wqkv/Wp via LDS-tile transpose) -> GEMM qkv (8-phase
// counted-vmcnt 128x256; V TRANSPOSED [bh][e][t]) -> flash attn (R13: 32x32
// swapped MFMA, in-reg softmax, cvt_pk+permlane32_swap, defer-rescale, dbuf
// swizzled K/V) -> GEMM out (8-phase 128x256, fp32 out).

typedef __bf16 bf16x8 __attribute__((ext_vector_type(8)));
typedef unsigned short ushort8v __attribute__((ext_vector_type(8)));
typedef float f32x4 __attribute__((ext_vector_type(4)));
typedef float f32x16 __attribute__((ext_vector_type(16)));
typedef __attribute__((address_space(1))) void gvoid_t;
typedef __attribute__((address_space(3))) void lvoid_t;

using hbf = __hip_bfloat16;

#define QSCALE (0.125f * 1.44269504088896f)  // 1/sqrt(HS) * log2(e)

static __device__ __forceinline__ void gload_lds16(const void* g, void* l) {
  __builtin_amdgcn_global_load_lds((gvoid_t*)g, (lvoid_t*)l, 16, 0, 0);
}

static __device__ __forceinline__ uint16_t b2u(float x) {
  hbf h = __float2bfloat16(x);
  return *reinterpret_cast<uint16_t*>(&h);
}

static __device__ __forceinline__ uint32_t cvtpk(float lo, float hi) {
  uint32_t r;
  asm("v_cvt_pk_bf16_f32 %0, %1, %2" : "=v"(r) : "v"(lo), "v"(hi));
  return r;
}

// v_permlane32_swap_b32: newX = {X.lo31 | Y.lo31->hi}, newY = {X.hi31->lo | Y.hi31}
static __device__ __forceinline__ void pl32swap(uint32_t& x, uint32_t& y) {
  asm volatile("v_permlane32_swap_b32 %0, %1" : "+v"(x), "+v"(y));
}

static __device__ __forceinline__ float max3f(float a, float b, float c) {
  return fmaxf(fmaxf(a, b), c);  // fuses to v_max3_f32
}

// ---------------- converters ----------------
// x + biases: both coalesced already.
__global__ void k_cvt_x_bias(const float* __restrict__ x,
                             const float* __restrict__ bq, const float* __restrict__ bk,
                             const float* __restrict__ bv,
                             hbf* __restrict__ xb, float* __restrict__ biasc) {
  const int b = blockIdx.x, tid = threadIdx.x;
  if (b < 8192) {
    int i = (b * 256 + tid) * 4;
    float4 v = *reinterpret_cast<const float4*>(x + i);
    hbf h[4] = {__float2bfloat16(v.x), __float2bfloat16(v.y),
                __float2bfloat16(v.z), __float2bfloat16(v.w)};
    *reinterpret_cast<ushort4*>(xb + i) = *reinterpret_cast<ushort4*>(h);
  } else {
    int r = (b - 8192) * 256 + tid;     // 0..3071
    int m = r >> 10, rem = r & 1023;
    const float* bsrc = (m == 0) ? bq : (m == 1) ? bk : bv;
    float v = bsrc[rem];
    if (m == 0) v *= QSCALE;
    biasc[r] = v;
  }
}

// Wq/Wk/Wv [h][d][e] -> Wt[(m,h,e)][d], transpose via LDS 64x64 tile.
// grid 768: m = b>>8, h = (b>>4)&15, d0 = (b&15)*64. Load: 4 row-groups of 16
// (256 thr x 4 iters x float4 = 4096 floats). Write: col reads stride 65
// (==1 mod 32), <=2-way.
__global__ void k_cvt_wqkv(const float* __restrict__ Wq, const float* __restrict__ Wk,
                           const float* __restrict__ Wv, hbf* __restrict__ Wt) {
  __shared__ float lds[64][65];
  const int b = blockIdx.x, tid = threadIdx.x;
  const int m = b >> 8, h = (b >> 4) & 15, d0 = (b & 15) * 64;
  const float* W = (m == 0) ? Wq : (m == 1) ? Wk : Wv;

  const int dr = tid >> 4, ec = (tid & 15) * 4;
#pragma unroll
  for (int p = 0; p < 4; ++p) {
    const int row = p * 16 + dr;
    float4 v = *reinterpret_cast<const float4*>(
        W + ((size_t)((h << 10) + d0 + row)) * 64 + ec);
    if (m == 0) { v.x *= QSCALE; v.y *= QSCALE; v.z *= QSCALE; v.w *= QSCALE; }
    lds[row][ec] = v.x; lds[row][ec + 1] = v.y;
    lds[row][ec + 2] = v.z; lds[row][ec + 3] = v.w;
  }
  __syncthreads();

  const int e = tid >> 2, dj = (tid & 3) * 16;
  uint16_t tmp[16];
#pragma unroll
  for (int j = 0; j < 16; ++j) tmp[j] = b2u(lds[dj + j][e]);
  hbf* dst = Wt + ((size_t)(m * 1024 + (h << 6) + e)) * 1024 + d0 + dj;
  *reinterpret_cast<ushort8v*>(dst) = *reinterpret_cast<ushort8v*>(tmp);
  *reinterpret_cast<ushort8v*>(dst + 8) = *reinterpret_cast<ushort8v*>(tmp + 8);
}

// Wp[d][o] -> Wpt[o][d], transpose via LDS 64x64 tile. grid 256: d0=(b>>4)*64,
// o0=(b&15)*64. Same 4-row-group load fix.
__global__ void k_cvt_wp(const float* __restrict__ Wp, hbf* __restrict__ Wpt) {
  __shared__ float lds[64][65];
  const int b = blockIdx.x, tid = threadIdx.x;
  const int d0 = (b >> 4) * 64, o0 = (b & 15) * 64;

  const int dr = tid >> 4, oc = (tid & 15) * 4;
#pragma unroll
  for (int p = 0; p < 4; ++p) {
    const int row = p * 16 + dr;
    float4 v = *reinterpret_cast<const float4*>(Wp + (size_t)(d0 + row) * 1024 + o0 + oc);
    lds[row][oc] = v.x; lds[row][oc + 1] = v.y;
    lds[row][oc + 2] = v.z; lds[row][oc + 3] = v.w;
  }
  __syncthreads();

  const int ol = tid >> 2, dj = (tid & 3) * 16;
  uint16_t tmp[16];
#pragma unroll
  for (int j = 0; j < 16; ++j) tmp[j] = b2u(lds[dj + j][ol]);
  hbf* dst = Wpt + (size_t)(o0 + ol) * 1024 + d0 + dj;
  *reinterpret_cast<ushort8v*>(dst) = *reinterpret_cast<ushort8v*>(tmp);
  *reinterpret_cast<ushort8v*>(dst + 8) = *reinterpret_cast<ushort8v*>(tmp + 8);
}

// ---------------- QKV projection GEMM (8-phase, R12-verified) ----------------

__global__ __launch_bounds__(512) void k_gemm_qkv(
    const hbf* __restrict__ A, const hbf* __restrict__ Bw,
    const float* __restrict__ biasc, hbf* __restrict__ qkv) {
  __shared__ __align__(16) hbf sA[2][128 * 64];
  __shared__ __align__(16) hbf sB[2][256 * 64];
  const int tid = threadIdx.x;
  const int lane = tid & 63, w = tid >> 6;
  const int wm = w >> 2, wn = w & 3;
  const int g = lane >> 4, cl = lane & 15;
  const int m0 = blockIdx.x * 128, n0 = blockIdx.y * 256;
  const int sr = tid >> 3, sc = tid & 7;

  const f32x4 fz = {0.f, 0.f, 0.f, 0.f};
  f32x4 acc[4][4];
#pragma unroll
  for (int a = 0; a < 4; ++a)
#pragma unroll
    for (int b = 0; b < 4; ++b) acc[a][b] = fz;

#pragma unroll
  for (int kt = 0; kt < 2; ++kt) {
#pragma unroll
    for (int s = 0; s < 2; ++s) {
      const int row = s * 64 + sr;
      gload_lds16(A + (size_t)(m0 + row) * 1024 + kt * 64 + ((sc ^ (row & 7)) * 8),
                  &sA[kt][s * 4096 + tid * 8]);
    }
#pragma unroll
    for (int s = 0; s < 4; ++s) {
      const int row = s * 64 + sr;
      gload_lds16(Bw + (size_t)(n0 + row) * 1024 + kt * 64 + ((sc ^ (row & 7)) * 8),
                  &sB[kt][s * 4096 + tid * 8]);
    }
  }
  asm volatile("s_waitcnt vmcnt(6)" ::: "memory");
  __builtin_amdgcn_s_barrier();

  for (int kt = 0; kt < 16; ++kt) {
    const int bi = kt & 1;
    const bool st = (kt + 2) < 16;

    bf16x8 af[4][2], bf[4][2];
#pragma unroll
    for (int rt = 0; rt < 4; ++rt)
#pragma unroll
      for (int ks = 0; ks < 2; ++ks)
        af[rt][ks] = *reinterpret_cast<const bf16x8*>(
            &sA[bi][(wm * 64 + rt * 16 + cl) * 64 + (((ks * 4 + g) ^ (cl & 7)) * 8)]);
#pragma unroll
    for (int ct = 0; ct < 4; ++ct)
#pragma unroll
      for (int ks = 0; ks < 2; ++ks)
        bf[ct][ks] = *reinterpret_cast<const bf16x8*>(
            &sB[bi][(wn * 64 + ct * 16 + cl) * 64 + (((ks * 4 + g) ^ (cl & 7)) * 8)]);
    __builtin_amdgcn_s_barrier();
    asm volatile("s_waitcnt lgkmcnt(0)" ::: "memory");
    __builtin_amdgcn_sched_barrier(0);
    __builtin_amdgcn_s_setprio(1);
#pragma unroll
    for (int rt = 0; rt < 4; ++rt)
#pragma unroll
      for (int ks = 0; ks < 2; ++ks)
        acc[rt][0] = __builtin_amdgcn_mfma_f32_16x16x32_bf16(af[rt][ks], bf[0][ks], acc[rt][0], 0, 0, 0);
    __builtin_amdgcn_s_setprio(0);
    __builtin_amdgcn_s_barrier();

#pragma unroll
    for (int q = 1; q < 4; ++q) {
      if (st) {
        if (q == 1) {
#pragma unroll
          for (int s = 0; s < 2; ++s) {
            const int row = s * 64 + sr;
            gload_lds16(A + (size_t)(m0 + row) * 1024 + (kt + 2) * 64 + ((sc ^ (row & 7)) * 8),
                        &sA[bi][s * 4096 + tid * 8]);
          }
        } else {
#pragma unroll
          for (int s2 = 0; s2 < 2; ++s2) {
            const int s = (q - 2) * 2 + s2;
            const int row = s * 64 + sr;
            gload_lds16(Bw + (size_t)(n0 + row) * 1024 + (kt + 2) * 64 + ((sc ^ (row & 7)) * 8),
                        &sB[bi][s * 4096 + tid * 8]);
          }
        }
      }
      __builtin_amdgcn_s_setprio(1);
#pragma unroll
      for (int rt = 0; rt < 4; ++rt)
#pragma unroll
        for (int ks = 0; ks < 2; ++ks)
          acc[rt][q] = __builtin_amdgcn_mfma_f32_16x16x32_bf16(af[rt][ks], bf[q][ks], acc[rt][q], 0, 0, 0);
      __builtin_amdgcn_s_setprio(0);
      if (q == 3) {
        if (st) asm volatile("s_waitcnt vmcnt(6)" ::: "memory");
        else    asm volatile("s_waitcnt vmcnt(0)" ::: "memory");
      }
      __builtin_amdgcn_s_barrier();
    }
  }

#pragma unroll
  for (int rt = 0; rt < 4; ++rt)
#pragma unroll
    for (int ct = 0; ct < 4; ++ct) {
      const int colg = n0 + wn * 64 + ct * 16 + cl;
      const int mi = colg >> 10, rem = colg & 1023;
      const int h = rem >> 6, e = rem & 63;
      const float bi_ = biasc[colg];
      if (mi == 2) {
        const int t0 = m0 + wm * 64 + rt * 16 + g * 4;
        const int b = t0 >> 12, t = t0 & 4095;
        ushort4 o;
        o.x = b2u(acc[rt][ct][0] + bi_);
        o.y = b2u(acc[rt][ct][1] + bi_);
        o.z = b2u(acc[rt][ct][2] + bi_);
        o.w = b2u(acc[rt][ct][3] + bi_);
        *reinterpret_cast<ushort4*>(
            qkv + (size_t)64 * 262144 + (size_t)(b * 16 + h) * 262144 + (size_t)e * 4096 + t) = o;
      } else {
#pragma unroll
        for (int i = 0; i < 4; ++i) {
          const int rowg = m0 + wm * 64 + rt * 16 + g * 4 + i;
          const int b = rowg >> 12, t = rowg & 4095;
          qkv[(((size_t)mi * 32 + b * 16 + h) * 4096 + t) * 64 + e] =
              __float2bfloat16(acc[rt][ct][i] + bi_);
        }
      }
    }
}

// ---------------- flash attention (R13, verified) ----------------

__global__ __launch_bounds__(256) void k_flash(
    const hbf* __restrict__ qkv, hbf* __restrict__ attn) {
  __shared__ __align__(16) __bf16 sK[2][64 * 64];
  __shared__ __align__(16) __bf16 sV[2][64 * 64];
  const int tid = threadIdx.x, lane = tid & 63, wq = tid >> 6;
  const int h = lane >> 5, r31 = lane & 31;
  const int bh = blockIdx.x;
  const int qtb = (int)gridDim.y - 1 - (int)blockIdx.y;  // 0..31
  const int q0 = qtb * 128;
  const int ntile = 2 * qtb + 2;
  const hbf* Q  = qkv + (size_t)bh * 262144;
  const hbf* Kp = qkv + (size_t)(32 + bh) * 262144;
  const hbf* Vp = qkv + (size_t)(64 + bh) * 262144;  // [e=64][t=4096]
  const float NEG_INF = -__builtin_inff();

  const int koff = (wq * 16 + (lane >> 3)) * 64 + (((lane & 7) ^ (lane >> 3)) * 8);
  const int voff = (wq * 16 + (lane >> 3)) * 4096 + (((lane & 7) ^ (lane >> 3)) * 8);

  const int qrow = q0 + wq * 32 + r31;
  bf16x8 aq[4];
#pragma unroll
  for (int ks = 0; ks < 4; ++ks)
    aq[ks] = *reinterpret_cast<const bf16x8*>(Q + (size_t)qrow * 64 + ks * 16 + h * 8);

  f32x16 accO[2];
#pragma unroll
  for (int et = 0; et < 2; ++et)
#pragma unroll
    for (int i = 0; i < 16; ++i) accO[et][i] = 0.f;
  float mrow = NEG_INF, lrow = 0.f;

  gload_lds16(Kp + koff,         &sK[0][wq * 1024]);
  gload_lds16(Kp + koff + 512,   &sK[0][wq * 1024 + 512]);
  gload_lds16(Vp + voff,         &sV[0][wq * 1024]);
  gload_lds16(Vp + voff + 32768, &sV[0][wq * 1024 + 512]);
  __syncthreads();

  const int qmaxw = q0 + wq * 32 + 31;
  int buf = 0;
  for (int jt = 0; jt < ntile; ++jt) {
    if (jt < ntile - 1) {
      const hbf* Kg = Kp + (size_t)(jt + 1) * 4096;
      gload_lds16(Kg + koff,       &sK[buf ^ 1][wq * 1024]);
      gload_lds16(Kg + koff + 512, &sK[buf ^ 1][wq * 1024 + 512]);
      const hbf* Vg = Vp + (jt + 1) * 64;
      gload_lds16(Vg + voff,         &sV[buf ^ 1][wq * 1024]);
      gload_lds16(Vg + voff + 32768, &sV[buf ^ 1][wq * 1024 + 512]);
    }

    if (64 * jt <= qmaxw) {
      const __bf16* sKb = sK[buf];
      const __bf16* sVb = sV[buf];

      f32x16 accS[2];
      __builtin_amdgcn_s_setprio(1);
#pragma unroll
      for (int t = 0; t < 2; ++t) {
        f32x16 s;
#pragma unroll
        for (int i = 0; i < 16; ++i) s[i] = 0.f;
#pragma unroll
        for (int ks = 0; ks < 4; ++ks) {
          bf16x8 ak = *reinterpret_cast<const bf16x8*>(
              sKb + (t * 32 + r31) * 64 + (((2 * ks + h) ^ (r31 & 7)) * 8));
          s = __builtin_amdgcn_mfma_f32_32x32x16_bf16(ak, aq[ks], s, 0, 0, 0);
        }
        accS[t] = s;
      }
      __builtin_amdgcn_s_setprio(0);

      if (64 * jt + 63 > q0 + wq * 32) {
#pragma unroll
        for (int t = 0; t < 2; ++t)
#pragma unroll
          for (int i = 0; i < 16; ++i) {
            const int kvg = 64 * jt + 32 * t + (i & 3) + 8 * (i >> 2) + 4 * h;
            if (kvg > qrow) accS[t][i] = NEG_INF;
          }
      }

      float g0 = max3f(accS[0][0], accS[0][1], accS[0][2]);
      float g1 = max3f(accS[0][3], accS[0][4], accS[0][5]);
      float g2 = max3f(accS[0][6], accS[0][7], accS[0][8]);
      float g3 = max3f(accS[0][9], accS[0][10], accS[0][11]);
      float g4 = max3f(accS[0][12], accS[0][13], accS[0][14]);
      float g5 = max3f(accS[0][15], accS[1][0], accS[1][1]);
      float g6 = max3f(accS[1][2], accS[1][3], accS[1][4]);
      float g7 = max3f(accS[1][5], accS[1][6], accS[1][7]);
      float g8 = max3f(accS[1][8], accS[1][9], accS[1][10]);
      float g9 = max3f(accS[1][11], accS[1][12], accS[1][13]);
      float gA = fmaxf(accS[1][14], accS[1][15]);
      float h0 = max3f(g0, g1, g2);
      float h1 = max3f(g3, g4, g5);
      float h2 = max3f(g6, g7, g8);
      float h3 = fmaxf(g9, gA);
      float pmax = fmaxf(max3f(h0, h1, h2), h3);
      pmax = fmaxf(pmax, __shfl_xor(pmax, 32));

      if (!__all(pmax - mrow <= 8.f)) {  // defer-rescale (T13)
        const float mn = fmaxf(mrow, pmax);
        const float corr = __builtin_amdgcn_exp2f(mrow - mn);
        mrow = mn;
        lrow *= corr;
#pragma unroll
        for (int et = 0; et < 2; ++et)
#pragma unroll
          for (int i = 0; i < 16; ++i) accO[et][i] *= corr;
      }

#pragma unroll
      for (int t = 0; t < 2; ++t)
#pragma unroll
        for (int i = 0; i < 16; ++i)
          accS[t][i] = __builtin_amdgcn_exp2f(accS[t][i] - mrow);
      float s0 = (accS[0][0] + accS[0][1]) + (accS[0][2] + accS[0][3]);
      float s1 = (accS[0][4] + accS[0][5]) + (accS[0][6] + accS[0][7]);
      float s2 = (accS[0][8] + accS[0][9]) + (accS[0][10] + accS[0][11]);
      float s3 = (accS[0][12] + accS[0][13]) + (accS[0][14] + accS[0][15]);
      float s4 = (accS[1][0] + accS[1][1]) + (accS[1][2] + accS[1][3]);
      float s5 = (accS[1][4] + accS[1][5]) + (accS[1][6] + accS[1][7]);
      float s6 = (accS[1][8] + accS[1][9]) + (accS[1][10] + accS[1][11]);
      float s7 = (accS[1][12] + accS[1][13]) + (accS[1][14] + accS[1][15]);
      float rs = ((s0 + s1) + (s2 + s3)) + ((s4 + s5) + (s6 + s7));
      rs += __shfl_xor(rs, 32);
      lrow += rs;

      uint32_t d0[2][4], d1[2][4];
#pragma unroll
      for (int t = 0; t < 2; ++t)
#pragma unroll
        for (int r4 = 0; r4 < 4; ++r4) {
          d0[t][r4] = cvtpk(accS[t][4 * r4 + 0], accS[t][4 * r4 + 1]);
          d1[t][r4] = cvtpk(accS[t][4 * r4 + 2], accS[t][4 * r4 + 3]);
        }

#pragma unroll
      for (int kb = 0; kb < 4; ++kb) {
        const int t = kb >> 1, ra = 2 * (kb & 1), rb = ra + 1;
        uint32_t x0 = d0[t][ra], y0 = d0[t][rb];
        uint32_t x1 = d1[t][ra], y1 = d1[t][rb];
        pl32swap(x0, y0);
        pl32swap(x1, y1);
        union { uint32_t u[4]; bf16x8 v; } bP;
        bP.u[0] = x0; bP.u[1] = x1; bP.u[2] = y0; bP.u[3] = y1;
        __builtin_amdgcn_s_setprio(1);
#pragma unroll
        for (int et = 0; et < 2; ++et) {
          bf16x8 av = *reinterpret_cast<const bf16x8*>(
              sVb + (et * 32 + r31) * 64 + (((2 * kb + h) ^ (r31 & 7)) * 8));
          accO[et] = __builtin_amdgcn_mfma_f32_32x32x16_bf16(av, bP.v, accO[et], 0, 0, 0);
        }
        __builtin_amdgcn_s_setprio(0);
      }
    }

    __syncthreads();
    buf ^= 1;
  }

  const float inv = 1.0f / lrow;
  hbf* arow = attn + ((size_t)(bh >> 4) * 4096 + qrow) * 1024 + (bh & 15) * 64;
#pragma unroll
  for (int et = 0; et < 2; ++et)
#pragma unroll
    for (int r4 = 0; r4 < 4; ++r4) {
      const int e0 = et * 32 + 8 * r4 + 4 * h;
      ushort4 o;
      o.x = b2u(accO[et][4 * r4 + 0] * inv);
      o.y = b2u(accO[et][4 * r4 + 1] * inv);
      o.z = b2u(accO[et][4 * r4 + 2] * inv);
      o.w = b2u(accO[et][4 * r4 + 3] * inv);
      *reinterpret_cast<ushort4*>(arow + e0) = o;
    }
}

// ---------------- output projection GEMM (8-phase 128x256, fp32 out) ----------------

__global__ __launch_bounds__(512) void k_gemm_out(
    const hbf* __restrict__ A, const hbf* __restrict__ Bw,
    const float* __restrict__ bp, float* __restrict__ out) {
  __shared__ __align__(16) hbf sA[2][128 * 64];
  __shared__ __align__(16) hbf sB[2][256 * 64];
  const int tid = threadIdx.x;
  const int lane = tid & 63, w = tid >> 6;
  const int wm = w >> 2, wn = w & 3;
  const int g = lane >> 4, cl = lane & 15;
  const int m0 = blockIdx.x * 128, n0 = blockIdx.y * 256;
  const int sr = tid >> 3, sc = tid & 7;

  const f32x4 fz = {0.f, 0.f, 0.f, 0.f};
  f32x4 acc[4][4];
#pragma unroll
  for (int a = 0; a < 4; ++a)
#pragma unroll
    for (int b = 0; b < 4; ++b) acc[a][b] = fz;

#pragma unroll
  for (int kt = 0; kt < 2; ++kt) {
#pragma unroll
    for (int s = 0; s < 2; ++s) {
      const int row = s * 64 + sr;
      gload_lds16(A + (size_t)(m0 + row) * 1024 + kt * 64 + ((sc ^ (row & 7)) * 8),
                  &sA[kt][s * 4096 + tid * 8]);
    }
#pragma unroll
    for (int s = 0; s < 4; ++s) {
      const int row = s * 64 + sr;
      gload_lds16(Bw + (size_t)(n0 + row) * 1024 + kt * 64 + ((sc ^ (row & 7)) * 8),
                  &sB[kt][s * 4096 + tid * 8]);
    }
  }
  asm volatile("s_waitcnt vmcnt(6)" ::: "memory");
  __builtin_amdgcn_s_barrier();

  for (int kt = 0; kt < 16; ++kt) {
    const int bi = kt & 1;
    const bool st = (kt + 2) < 16;

    bf16x8 af[4][2], bf[4][2];
#pragma unroll
    for (int rt = 0; rt < 4; ++rt)
#pragma unroll
      for (int ks = 0; ks < 2; ++ks)
        af[rt][ks] = *reinterpret_cast<const bf16x8*>(
            &sA[bi][(wm * 64 + rt * 16 + cl) * 64 + (((ks * 4 + g) ^ (cl & 7)) * 8)]);
#pragma unroll
    for (int ct = 0; ct < 4; ++ct)
#pragma unroll
      for (int ks = 0; ks < 2; ++ks)
        bf[ct][ks] = *reinterpret_cast<const bf16x8*>(
            &sB[bi][(wn * 64 + ct * 16 + cl) * 64 + (((ks * 4 + g) ^ (cl & 7)) * 8)]);
    __builtin_amdgcn_s_barrier();
    asm volatile("s_waitcnt lgkmcnt(0)" ::: "memory");
    __builtin_amdgcn_sched_barrier(0);
    __builtin_amdgcn_s_setprio(1);
#pragma unroll
    for (int rt = 0; rt < 4; ++rt)
#pragma unroll
      for (int ks = 0; ks < 2; ++ks)
        acc[rt][0] = __builtin_amdgcn_mfma_f32_16x16x32_bf16(af[rt][ks], bf[0][ks], acc[rt][0], 0, 0, 0);
    __builtin_amdgcn_s_setprio(0);
    __builtin_amdgcn_s_barrier();

#pragma unroll
    for (int q = 1; q < 4; ++q) {
      if (st) {
        if (q == 1) {
#pragma unroll
          for (int s = 0; s < 2; ++s) {
            const int row = s * 64 + sr;
            gload_lds16(A + (size_t)(m0 + row) * 1024 + (kt + 2) * 64 + ((sc ^ (row & 7)) * 8),
                        &sA[bi][s * 4096 + tid * 8]);
          }
        } else {
#pragma unroll
          for (int s2 = 0; s2 < 2; ++s2) {
            const int s = (q - 2) * 2 + s2;
            const int row = s * 64 + sr;
            gload_lds16(Bw + (size_t)(n0 + row) * 1024 + (kt + 2) * 64 + ((sc ^ (row & 7)) * 8),
                        &sB[bi][s * 4096 + tid * 8]);
          }
        }
      }
      __builtin_amdgcn_s_setprio(1);
#pragma unroll
      for (int rt = 0; rt < 4; ++rt)
#pragma unroll
        for (int ks = 0; ks < 2; ++ks)
          acc[rt][q] = __builtin_amdgcn_mfma_f32_16x16x32_bf16(af[rt][ks], bf[q][ks], acc[rt][q], 0, 0, 0);
      __builtin_amdgcn_s_setprio(0);
      if (q == 3) {
        if (st) asm volatile("s_waitcnt vmcnt(6)" ::: "memory");
        else    asm volatile("s_waitcnt vmcnt(0)" ::: "memory");
      }
      __builtin_amdgcn_s_barrier();
    }
  }

#pragma unroll
  for (int rt = 0; rt < 4; ++rt)
#pragma unroll
    for (int ct = 0; ct < 4; ++ct) {
      const int colg = n0 + wn * 64 + ct * 16 + cl;
      const float bi_ = bp[colg];
#pragma unroll
      for (int i = 0; i < 4; ++i) {
        const int rowg = m0 + wm * 64 + rt * 16 + g * 4 + i;
        out[(size_t)rowg * 1024 + colg] = acc[rt][ct][i] + bi_;
      }
    }
}

// ---------------- launcher ----------------

extern "C" void kernel_launch(void* const* d_in, const int* in_sizes, int n_in,
                              void* d_out, int out_size, void* d_ws, size_t ws_size,
                              hipStream_t stream) {
  const float* x  = (const float*)d_in[0];
  const float* Wq = (const float*)d_in[1];
  const float* Wk = (const float*)d_in[2];
  const float* Wv = (const float*)d_in[3];
  const float* bq = (const float*)d_in[4];
  const float* bk = (const float*)d_in[5];
  const float* bv = (const float*)d_in[6];
  const float* Wp = (const float*)d_in[7];
  const float* bp = (const float*)d_in[8];
  float* out = (float*)d_out;

  char* ws = (char*)d_ws;
  hbf*   xb    = (hbf*)ws;                                   // 16 MiB (reused as attn_out)
  hbf*   Wt    = (hbf*)(ws + 16777216);                      // 6 MiB
  hbf*   Wpt   = (hbf*)(ws + 16777216 + 6291456);            // 2 MiB
  float* biasc = (float*)(ws + 16777216 + 6291456 + 2097152);// 12 KiB (+pad)
  hbf*   qkv   = (hbf*)(ws + 16777216 + 6291456 + 2097152 + 16384); // 48 MiB
  hbf*   attn  = xb;

  k_cvt_x_bias<<<8204, 256, 0, stream>>>(x, bq, bk, bv, xb, biasc);
  k_cvt_wqkv  <<<768,  256, 0, stream>>>(Wq, Wk, Wv, Wt);
  k_cvt_wp    <<<256,  256, 0, stream>>>(Wp, Wpt);

  dim3 g1(64, 12); k_gemm_qkv<<<g1, 512, 0, stream>>>(xb, Wt, biasc, qkv);
  dim3 g2(32, 32); k_flash   <<<g2, 256, 0, stream>>>(qkv, attn);
  dim3 g3(64, 4);  k_gemm_out<<<g3, 512, 0, stream>>>(attn, Wpt, bp, out);
}

// Round 17
// 198.929 us; speedup vs baseline: 1.1322x; 1.0351x over previous
//
#include <hip/hip_runtime.h>
#include <hip/hip_bf16.h>
#include <stdint.h>

// B=2, T=4096, D=1024, H=16, HS=64. Pipeline:
// cvt (x+bias coalesced; Wqkv/Wp LDS-transpose) -> GEMM qkv (8-phase 128x256;
// V TRANSPOSED [bh][e][t]) -> flash attn (Q-tile 256, 8 waves x 32 q-rows,
// 32x32 swapped MFMA, in-reg softmax, cvt_pk+permlane32_swap, defer-rescale,
// dbuf swizzled K/V, balanced qtb pairs) -> GEMM out (8-phase, fp32 out).

typedef __bf16 bf16x8 __attribute__((ext_vector_type(8)));
typedef unsigned short ushort8v __attribute__((ext_vector_type(8)));
typedef float f32x4 __attribute__((ext_vector_type(4)));
typedef float f32x16 __attribute__((ext_vector_type(16)));
typedef __attribute__((address_space(1))) void gvoid_t;
typedef __attribute__((address_space(3))) void lvoid_t;

using hbf = __hip_bfloat16;

#define QSCALE (0.125f * 1.44269504088896f)  // 1/sqrt(HS) * log2(e)

static __device__ __forceinline__ void gload_lds16(const void* g, void* l) {
  __builtin_amdgcn_global_load_lds((gvoid_t*)g, (lvoid_t*)l, 16, 0, 0);
}

static __device__ __forceinline__ uint16_t b2u(float x) {
  hbf h = __float2bfloat16(x);
  return *reinterpret_cast<uint16_t*>(&h);
}

static __device__ __forceinline__ uint32_t cvtpk(float lo, float hi) {
  uint32_t r;
  asm("v_cvt_pk_bf16_f32 %0, %1, %2" : "=v"(r) : "v"(lo), "v"(hi));
  return r;
}

// v_permlane32_swap_b32: newX = {X.lo31 | Y.lo31->hi}, newY = {X.hi31->lo | Y.hi31}
static __device__ __forceinline__ void pl32swap(uint32_t& x, uint32_t& y) {
  asm volatile("v_permlane32_swap_b32 %0, %1" : "+v"(x), "+v"(y));
}

static __device__ __forceinline__ float max3f(float a, float b, float c) {
  return fmaxf(fmaxf(a, b), c);  // fuses to v_max3_f32
}

// ---------------- converters ----------------

__global__ void k_cvt_x_bias(const float* __restrict__ x,
                             const float* __restrict__ bq, const float* __restrict__ bk,
                             const float* __restrict__ bv,
                             hbf* __restrict__ xb, float* __restrict__ biasc) {
  const int b = blockIdx.x, tid = threadIdx.x;
  if (b < 8192) {
    int i = (b * 256 + tid) * 4;
    float4 v = *reinterpret_cast<const float4*>(x + i);
    hbf h[4] = {__float2bfloat16(v.x), __float2bfloat16(v.y),
                __float2bfloat16(v.z), __float2bfloat16(v.w)};
    *reinterpret_cast<ushort4*>(xb + i) = *reinterpret_cast<ushort4*>(h);
  } else {
    int r = (b - 8192) * 256 + tid;     // 0..3071
    int m = r >> 10, rem = r & 1023;
    const float* bsrc = (m == 0) ? bq : (m == 1) ? bk : bv;
    float v = bsrc[rem];
    if (m == 0) v *= QSCALE;
    biasc[r] = v;
  }
}

__global__ void k_cvt_wqkv(const float* __restrict__ Wq, const float* __restrict__ Wk,
                           const float* __restrict__ Wv, hbf* __restrict__ Wt) {
  __shared__ float lds[64][65];
  const int b = blockIdx.x, tid = threadIdx.x;
  const int m = b >> 8, h = (b >> 4) & 15, d0 = (b & 15) * 64;
  const float* W = (m == 0) ? Wq : (m == 1) ? Wk : Wv;

  const int dr = tid >> 4, ec = (tid & 15) * 4;
#pragma unroll
  for (int p = 0; p < 4; ++p) {
    const int row = p * 16 + dr;
    float4 v = *reinterpret_cast<const float4*>(
        W + ((size_t)((h << 10) + d0 + row)) * 64 + ec);
    if (m == 0) { v.x *= QSCALE; v.y *= QSCALE; v.z *= QSCALE; v.w *= QSCALE; }
    lds[row][ec] = v.x; lds[row][ec + 1] = v.y;
    lds[row][ec + 2] = v.z; lds[row][ec + 3] = v.w;
  }
  __syncthreads();

  const int e = tid >> 2, dj = (tid & 3) * 16;
  uint16_t tmp[16];
#pragma unroll
  for (int j = 0; j < 16; ++j) tmp[j] = b2u(lds[dj + j][e]);
  hbf* dst = Wt + ((size_t)(m * 1024 + (h << 6) + e)) * 1024 + d0 + dj;
  *reinterpret_cast<ushort8v*>(dst) = *reinterpret_cast<ushort8v*>(tmp);
  *reinterpret_cast<ushort8v*>(dst + 8) = *reinterpret_cast<ushort8v*>(tmp + 8);
}

__global__ void k_cvt_wp(const float* __restrict__ Wp, hbf* __restrict__ Wpt) {
  __shared__ float lds[64][65];
  const int b = blockIdx.x, tid = threadIdx.x;
  const int d0 = (b >> 4) * 64, o0 = (b & 15) * 64;

  const int dr = tid >> 4, oc = (tid & 15) * 4;
#pragma unroll
  for (int p = 0; p < 4; ++p) {
    const int row = p * 16 + dr;
    float4 v = *reinterpret_cast<const float4*>(Wp + (size_t)(d0 + row) * 1024 + o0 + oc);
    lds[row][oc] = v.x; lds[row][oc + 1] = v.y;
    lds[row][oc + 2] = v.z; lds[row][oc + 3] = v.w;
  }
  __syncthreads();

  const int ol = tid >> 2, dj = (tid & 3) * 16;
  uint16_t tmp[16];
#pragma unroll
  for (int j = 0; j < 16; ++j) tmp[j] = b2u(lds[dj + j][ol]);
  hbf* dst = Wpt + (size_t)(o0 + ol) * 1024 + d0 + dj;
  *reinterpret_cast<ushort8v*>(dst) = *reinterpret_cast<ushort8v*>(tmp);
  *reinterpret_cast<ushort8v*>(dst + 8) = *reinterpret_cast<ushort8v*>(tmp + 8);
}

// ---------------- QKV projection GEMM (8-phase, R12-verified) ----------------

__global__ __launch_bounds__(512) void k_gemm_qkv(
    const hbf* __restrict__ A, const hbf* __restrict__ Bw,
    const float* __restrict__ biasc, hbf* __restrict__ qkv) {
  __shared__ __align__(16) hbf sA[2][128 * 64];
  __shared__ __align__(16) hbf sB[2][256 * 64];
  const int tid = threadIdx.x;
  const int lane = tid & 63, w = tid >> 6;
  const int wm = w >> 2, wn = w & 3;
  const int g = lane >> 4, cl = lane & 15;
  const int m0 = blockIdx.x * 128, n0 = blockIdx.y * 256;
  const int sr = tid >> 3, sc = tid & 7;

  const f32x4 fz = {0.f, 0.f, 0.f, 0.f};
  f32x4 acc[4][4];
#pragma unroll
  for (int a = 0; a < 4; ++a)
#pragma unroll
    for (int b = 0; b < 4; ++b) acc[a][b] = fz;

#pragma unroll
  for (int kt = 0; kt < 2; ++kt) {
#pragma unroll
    for (int s = 0; s < 2; ++s) {
      const int row = s * 64 + sr;
      gload_lds16(A + (size_t)(m0 + row) * 1024 + kt * 64 + ((sc ^ (row & 7)) * 8),
                  &sA[kt][s * 4096 + tid * 8]);
    }
#pragma unroll
    for (int s = 0; s < 4; ++s) {
      const int row = s * 64 + sr;
      gload_lds16(Bw + (size_t)(n0 + row) * 1024 + kt * 64 + ((sc ^ (row & 7)) * 8),
                  &sB[kt][s * 4096 + tid * 8]);
    }
  }
  asm volatile("s_waitcnt vmcnt(6)" ::: "memory");
  __builtin_amdgcn_s_barrier();

  for (int kt = 0; kt < 16; ++kt) {
    const int bi = kt & 1;
    const bool st = (kt + 2) < 16;

    bf16x8 af[4][2], bf[4][2];
#pragma unroll
    for (int rt = 0; rt < 4; ++rt)
#pragma unroll
      for (int ks = 0; ks < 2; ++ks)
        af[rt][ks] = *reinterpret_cast<const bf16x8*>(
            &sA[bi][(wm * 64 + rt * 16 + cl) * 64 + (((ks * 4 + g) ^ (cl & 7)) * 8)]);
#pragma unroll
    for (int ct = 0; ct < 4; ++ct)
#pragma unroll
      for (int ks = 0; ks < 2; ++ks)
        bf[ct][ks] = *reinterpret_cast<const bf16x8*>(
            &sB[bi][(wn * 64 + ct * 16 + cl) * 64 + (((ks * 4 + g) ^ (cl & 7)) * 8)]);
    __builtin_amdgcn_s_barrier();
    asm volatile("s_waitcnt lgkmcnt(0)" ::: "memory");
    __builtin_amdgcn_sched_barrier(0);
    __builtin_amdgcn_s_setprio(1);
#pragma unroll
    for (int rt = 0; rt < 4; ++rt)
#pragma unroll
      for (int ks = 0; ks < 2; ++ks)
        acc[rt][0] = __builtin_amdgcn_mfma_f32_16x16x32_bf16(af[rt][ks], bf[0][ks], acc[rt][0], 0, 0, 0);
    __builtin_amdgcn_s_setprio(0);
    __builtin_amdgcn_s_barrier();

#pragma unroll
    for (int q = 1; q < 4; ++q) {
      if (st) {
        if (q == 1) {
#pragma unroll
          for (int s = 0; s < 2; ++s) {
            const int row = s * 64 + sr;
            gload_lds16(A + (size_t)(m0 + row) * 1024 + (kt + 2) * 64 + ((sc ^ (row & 7)) * 8),
                        &sA[bi][s * 4096 + tid * 8]);
          }
        } else {
#pragma unroll
          for (int s2 = 0; s2 < 2; ++s2) {
            const int s = (q - 2) * 2 + s2;
            const int row = s * 64 + sr;
            gload_lds16(Bw + (size_t)(n0 + row) * 1024 + (kt + 2) * 64 + ((sc ^ (row & 7)) * 8),
                        &sB[bi][s * 4096 + tid * 8]);
          }
        }
      }
      __builtin_amdgcn_s_setprio(1);
#pragma unroll
      for (int rt = 0; rt < 4; ++rt)
#pragma unroll
        for (int ks = 0; ks < 2; ++ks)
          acc[rt][q] = __builtin_amdgcn_mfma_f32_16x16x32_bf16(af[rt][ks], bf[q][ks], acc[rt][q], 0, 0, 0);
      __builtin_amdgcn_s_setprio(0);
      if (q == 3) {
        if (st) asm volatile("s_waitcnt vmcnt(6)" ::: "memory");
        else    asm volatile("s_waitcnt vmcnt(0)" ::: "memory");
      }
      __builtin_amdgcn_s_barrier();
    }
  }

#pragma unroll
  for (int rt = 0; rt < 4; ++rt)
#pragma unroll
    for (int ct = 0; ct < 4; ++ct) {
      const int colg = n0 + wn * 64 + ct * 16 + cl;
      const int mi = colg >> 10, rem = colg & 1023;
      const int h = rem >> 6, e = rem & 63;
      const float bi_ = biasc[colg];
      if (mi == 2) {
        const int t0 = m0 + wm * 64 + rt * 16 + g * 4;
        const int b = t0 >> 12, t = t0 & 4095;
        ushort4 o;
        o.x = b2u(acc[rt][ct][0] + bi_);
        o.y = b2u(acc[rt][ct][1] + bi_);
        o.z = b2u(acc[rt][ct][2] + bi_);
        o.w = b2u(acc[rt][ct][3] + bi_);
        *reinterpret_cast<ushort4*>(
            qkv + (size_t)64 * 262144 + (size_t)(b * 16 + h) * 262144 + (size_t)e * 4096 + t) = o;
      } else {
#pragma unroll
        for (int i = 0; i < 4; ++i) {
          const int rowg = m0 + wm * 64 + rt * 16 + g * 4 + i;
          const int b = rowg >> 12, t = rowg & 4095;
          qkv[(((size_t)mi * 32 + b * 16 + h) * 4096 + t) * 64 + e] =
              __float2bfloat16(acc[rt][ct][i] + bi_);
        }
      }
    }
}

// ---------------- flash attention (Q-tile 256, 8 waves) ----------------
// grid (bh=32, 16); qtb = y<8 ? 15-y : y-8 (balanced 68-iter pairs per CU).
// 8 waves x 32 q-rows = 256 q; per-wave compute identical to R13-verified.
// 512 threads stage the 64x64 K and V^T tiles with ONE gload_lds16 each.

__global__ __launch_bounds__(512) void k_flash(
    const hbf* __restrict__ qkv, hbf* __restrict__ attn) {
  __shared__ __align__(16) __bf16 sK[2][64 * 64];
  __shared__ __align__(16) __bf16 sV[2][64 * 64];
  const int tid = threadIdx.x, lane = tid & 63, wq = tid >> 6;  // wq in [0,8)
  const int h = lane >> 5, r31 = lane & 31;
  const int bh = blockIdx.x;
  const int y = (int)blockIdx.y;
  const int qtb = (y < 8) ? (15 - y) : (y - 8);   // 0..15
  const int q0 = qtb * 256;
  const int ntile = 4 * qtb + 4;
  const hbf* Q  = qkv + (size_t)bh * 262144;
  const hbf* Kp = qkv + (size_t)(32 + bh) * 262144;
  const hbf* Vp = qkv + (size_t)(64 + bh) * 262144;  // [e=64][t=4096]
  const float NEG_INF = -__builtin_inff();

  // staging: thread covers row sr = tid>>3, chunk sc = tid&7 (src pre-swizzled)
  const int sr = tid >> 3, sc = tid & 7;
  const int koff = sr * 64 + ((sc ^ (sr & 7)) * 8);        // K[t=row][e-chunk]
  const int voff = sr * 4096 + ((sc ^ (sr & 7)) * 8);      // V^T[e=row][t-chunk]

  const int qrow = q0 + wq * 32 + r31;
  bf16x8 aq[4];
#pragma unroll
  for (int ks = 0; ks < 4; ++ks)
    aq[ks] = *reinterpret_cast<const bf16x8*>(Q + (size_t)qrow * 64 + ks * 16 + h * 8);

  f32x16 accO[2];
#pragma unroll
  for (int et = 0; et < 2; ++et)
#pragma unroll
    for (int i = 0; i < 16; ++i) accO[et][i] = 0.f;
  float mrow = NEG_INF, lrow = 0.f;

  gload_lds16(Kp + koff, &sK[0][tid * 8]);
  gload_lds16(Vp + voff, &sV[0][tid * 8]);
  __syncthreads();

  const int qmaxw = q0 + wq * 32 + 31;
  int buf = 0;
  for (int jt = 0; jt < ntile; ++jt) {
    if (jt < ntile - 1) {  // prefetch next tile (pure DMA)
      gload_lds16(Kp + (size_t)(jt + 1) * 4096 + koff, &sK[buf ^ 1][tid * 8]);
      gload_lds16(Vp + (jt + 1) * 64 + voff,           &sV[buf ^ 1][tid * 8]);
    }

    if (64 * jt <= qmaxw) {  // wave has unmasked work in this tile
      const __bf16* sKb = sK[buf];
      const __bf16* sVb = sV[buf];

      f32x16 accS[2];
      __builtin_amdgcn_s_setprio(1);
#pragma unroll
      for (int t = 0; t < 2; ++t) {
        f32x16 s;
#pragma unroll
        for (int i = 0; i < 16; ++i) s[i] = 0.f;
#pragma unroll
        for (int ks = 0; ks < 4; ++ks) {
          bf16x8 ak = *reinterpret_cast<const bf16x8*>(
              sKb + (t * 32 + r31) * 64 + (((2 * ks + h) ^ (r31 & 7)) * 8));
          s = __builtin_amdgcn_mfma_f32_32x32x16_bf16(ak, aq[ks], s, 0, 0, 0);
        }
        accS[t] = s;
      }
      __builtin_amdgcn_s_setprio(0);

      if (64 * jt + 63 > q0 + wq * 32) {  // diagonal region: mask kv > q
#pragma unroll
        for (int t = 0; t < 2; ++t)
#pragma unroll
          for (int i = 0; i < 16; ++i) {
            const int kvg = 64 * jt + 32 * t + (i & 3) + 8 * (i >> 2) + 4 * h;
            if (kvg > qrow) accS[t][i] = NEG_INF;
          }
      }

      float g0 = max3f(accS[0][0], accS[0][1], accS[0][2]);
      float g1 = max3f(accS[0][3], accS[0][4], accS[0][5]);
      float g2 = max3f(accS[0][6], accS[0][7], accS[0][8]);
      float g3 = max3f(accS[0][9], accS[0][10], accS[0][11]);
      float g4 = max3f(accS[0][12], accS[0][13], accS[0][14]);
      float g5 = max3f(accS[0][15], accS[1][0], accS[1][1]);
      float g6 = max3f(accS[1][2], accS[1][3], accS[1][4]);
      float g7 = max3f(accS[1][5], accS[1][6], accS[1][7]);
      float g8 = max3f(accS[1][8], accS[1][9], accS[1][10]);
      float g9 = max3f(accS[1][11], accS[1][12], accS[1][13]);
      float gA = fmaxf(accS[1][14], accS[1][15]);
      float h0 = max3f(g0, g1, g2);
      float h1 = max3f(g3, g4, g5);
      float h2 = max3f(g6, g7, g8);
      float h3 = fmaxf(g9, gA);
      float pmax = fmaxf(max3f(h0, h1, h2), h3);
      pmax = fmaxf(pmax, __shfl_xor(pmax, 32));

      if (!__all(pmax - mrow <= 8.f)) {  // defer-rescale (T13)
        const float mn = fmaxf(mrow, pmax);
        const float corr = __builtin_amdgcn_exp2f(mrow - mn);
        mrow = mn;
        lrow *= corr;
#pragma unroll
        for (int et = 0; et < 2; ++et)
#pragma unroll
          for (int i = 0; i < 16; ++i) accO[et][i] *= corr;
      }

#pragma unroll
      for (int t = 0; t < 2; ++t)
#pragma unroll
        for (int i = 0; i < 16; ++i)
          accS[t][i] = __builtin_amdgcn_exp2f(accS[t][i] - mrow);
      float s0 = (accS[0][0] + accS[0][1]) + (accS[0][2] + accS[0][3]);
      float s1 = (accS[0][4] + accS[0][5]) + (accS[0][6] + accS[0][7]);
      float s2 = (accS[0][8] + accS[0][9]) + (accS[0][10] + accS[0][11]);
      float s3 = (accS[0][12] + accS[0][13]) + (accS[0][14] + accS[0][15]);
      float s4 = (accS[1][0] + accS[1][1]) + (accS[1][2] + accS[1][3]);
      float s5 = (accS[1][4] + accS[1][5]) + (accS[1][6] + accS[1][7]);
      float s6 = (accS[1][8] + accS[1][9]) + (accS[1][10] + accS[1][11]);
      float s7 = (accS[1][12] + accS[1][13]) + (accS[1][14] + accS[1][15]);
      float rs = ((s0 + s1) + (s2 + s3)) + ((s4 + s5) + (s6 + s7));
      rs += __shfl_xor(rs, 32);
      lrow += rs;

      uint32_t d0[2][4], d1[2][4];
#pragma unroll
      for (int t = 0; t < 2; ++t)
#pragma unroll
        for (int r4 = 0; r4 < 4; ++r4) {
          d0[t][r4] = cvtpk(accS[t][4 * r4 + 0], accS[t][4 * r4 + 1]);
          d1[t][r4] = cvtpk(accS[t][4 * r4 + 2], accS[t][4 * r4 + 3]);
        }

#pragma unroll
      for (int kb = 0; kb < 4; ++kb) {
        const int t = kb >> 1, ra = 2 * (kb & 1), rb = ra + 1;
        uint32_t x0 = d0[t][ra], y0 = d0[t][rb];
        uint32_t x1 = d1[t][ra], y1 = d1[t][rb];
        pl32swap(x0, y0);
        pl32swap(x1, y1);
        union { uint32_t u[4]; bf16x8 v; } bP;
        bP.u[0] = x0; bP.u[1] = x1; bP.u[2] = y0; bP.u[3] = y1;
        __builtin_amdgcn_s_setprio(1);
#pragma unroll
        for (int et = 0; et < 2; ++et) {
          bf16x8 av = *reinterpret_cast<const bf16x8*>(
              sVb + (et * 32 + r31) * 64 + (((2 * kb + h) ^ (r31 & 7)) * 8));
          accO[et] = __builtin_amdgcn_mfma_f32_32x32x16_bf16(av, bP.v, accO[et], 0, 0, 0);
        }
        __builtin_amdgcn_s_setprio(0);
      }
    }

    __syncthreads();
    buf ^= 1;
  }

  const float inv = 1.0f / lrow;
  hbf* arow = attn + ((size_t)(bh >> 4) * 4096 + qrow) * 1024 + (bh & 15) * 64;
#pragma unroll
  for (int et = 0; et < 2; ++et)
#pragma unroll
    for (int r4 = 0; r4 < 4; ++r4) {
      const int e0 = et * 32 + 8 * r4 + 4 * h;
      ushort4 o;
      o.x = b2u(accO[et][4 * r4 + 0] * inv);
      o.y = b2u(accO[et][4 * r4 + 1] * inv);
      o.z = b2u(accO[et][4 * r4 + 2] * inv);
      o.w = b2u(accO[et][4 * r4 + 3] * inv);
      *reinterpret_cast<ushort4*>(arow + e0) = o;
    }
}

// ---------------- output projection GEMM (8-phase 128x256, fp32 out) ----------------

__global__ __launch_bounds__(512) void k_gemm_out(
    const hbf* __restrict__ A, const hbf* __restrict__ Bw,
    const float* __restrict__ bp, float* __restrict__ out) {
  __shared__ __align__(16) hbf sA[2][128 * 64];
  __shared__ __align__(16) hbf sB[2][256 * 64];
  const int tid = threadIdx.x;
  const int lane = tid & 63, w = tid >> 6;
  const int wm = w >> 2, wn = w & 3;
  const int g = lane >> 4, cl = lane & 15;
  const int m0 = blockIdx.x * 128, n0 = blockIdx.y * 256;
  const int sr = tid >> 3, sc = tid & 7;

  const f32x4 fz = {0.f, 0.f, 0.f, 0.f};
  f32x4 acc[4][4];
#pragma unroll
  for (int a = 0; a < 4; ++a)
#pragma unroll
    for (int b = 0; b < 4; ++b) acc[a][b] = fz;

#pragma unroll
  for (int kt = 0; kt < 2; ++kt) {
#pragma unroll
    for (int s = 0; s < 2; ++s) {
      const int row = s * 64 + sr;
      gload_lds16(A + (size_t)(m0 + row) * 1024 + kt * 64 + ((sc ^ (row & 7)) * 8),
                  &sA[kt][s * 4096 + tid * 8]);
    }
#pragma unroll
    for (int s = 0; s < 4; ++s) {
      const int row = s * 64 + sr;
      gload_lds16(Bw + (size_t)(n0 + row) * 1024 + kt * 64 + ((sc ^ (row & 7)) * 8),
                  &sB[kt][s * 4096 + tid * 8]);
    }
  }
  asm volatile("s_waitcnt vmcnt(6)" ::: "memory");
  __builtin_amdgcn_s_barrier();

  for (int kt = 0; kt < 16; ++kt) {
    const int bi = kt & 1;
    const bool st = (kt + 2) < 16;

    bf16x8 af[4][2], bf[4][2];
#pragma unroll
    for (int rt = 0; rt < 4; ++rt)
#pragma unroll
      for (int ks = 0; ks < 2; ++ks)
        af[rt][ks] = *reinterpret_cast<const bf16x8*>(
            &sA[bi][(wm * 64 + rt * 16 + cl) * 64 + (((ks * 4 + g) ^ (cl & 7)) * 8)]);
#pragma unroll
    for (int ct = 0; ct < 4; ++ct)
#pragma unroll
      for (int ks = 0; ks < 2; ++ks)
        bf[ct][ks] = *reinterpret_cast<const bf16x8*>(
            &sB[bi][(wn * 64 + ct * 16 + cl) * 64 + (((ks * 4 + g) ^ (cl & 7)) * 8)]);
    __builtin_amdgcn_s_barrier();
    asm volatile("s_waitcnt lgkmcnt(0)" ::: "memory");
    __builtin_amdgcn_sched_barrier(0);
    __builtin_amdgcn_s_setprio(1);
#pragma unroll
    for (int rt = 0; rt < 4; ++rt)
#pragma unroll
      for (int ks = 0; ks < 2; ++ks)
        acc[rt][0] = __builtin_amdgcn_mfma_f32_16x16x32_bf16(af[rt][ks], bf[0][ks], acc[rt][0], 0, 0, 0);
    __builtin_amdgcn_s_setprio(0);
    __builtin_amdgcn_s_barrier();

#pragma unroll
    for (int q = 1; q < 4; ++q) {
      if (st) {
        if (q == 1) {
#pragma unroll
          for (int s = 0; s < 2; ++s) {
            const int row = s * 64 + sr;
            gload_lds16(A + (size_t)(m0 + row) * 1024 + (kt + 2) * 64 + ((sc ^ (row & 7)) * 8),
                        &sA[bi][s * 4096 + tid * 8]);
          }
        } else {
#pragma unroll
          for (int s2 = 0; s2 < 2; ++s2) {
            const int s = (q - 2) * 2 + s2;
            const int row = s * 64 + sr;
            gload_lds16(Bw + (size_t)(n0 + row) * 1024 + (kt + 2) * 64 + ((sc ^ (row & 7)) * 8),
                        &sB[bi][s * 4096 + tid * 8]);
          }
        }
      }
      __builtin_amdgcn_s_setprio(1);
#pragma unroll
      for (int rt = 0; rt < 4; ++rt)
#pragma unroll
        for (int ks = 0; ks < 2; ++ks)
          acc[rt][q] = __builtin_amdgcn_mfma_f32_16x16x32_bf16(af[rt][ks], bf[q][ks], acc[rt][q], 0, 0, 0);
      __builtin_amdgcn_s_setprio(0);
      if (q == 3) {
        if (st) asm volatile("s_waitcnt vmcnt(6)" ::: "memory");
        else    asm volatile("s_waitcnt vmcnt(0)" ::: "memory");
      }
      __builtin_amdgcn_s_barrier();
    }
  }

#pragma unroll
  for (int rt = 0; rt < 4; ++rt)
#pragma unroll
    for (int ct = 0; ct < 4; ++ct) {
      const int colg = n0 + wn * 64 + ct * 16 + cl;
      const float bi_ = bp[colg];
#pragma unroll
      for (int i = 0; i < 4; ++i) {
        const int rowg = m0 + wm * 64 + rt * 16 + g * 4 + i;
        out[(size_t)rowg * 1024 + colg] = acc[rt][ct][i] + bi_;
      }
    }
}

// ---------------- launcher ----------------

extern "C" void kernel_launch(void* const* d_in, const int* in_sizes, int n_in,
                              void* d_out, int out_size, void* d_ws, size_t ws_size,
                              hipStream_t stream) {
  const float* x  = (const float*)d_in[0];
  const float* Wq = (const float*)d_in[1];
  const float* Wk = (const float*)d_in[2];
  const float* Wv = (const float*)d_in[3];
  const float* bq = (const float*)d_in[4];
  const float* bk = (const float*)d_in[5];
  const float* bv = (const float*)d_in[6];
  const float* Wp = (const float*)d_in[7];
  const float* bp = (const float*)d_in[8];
  float* out = (float*)d_out;

  char* ws = (char*)d_ws;
  hbf*   xb    = (hbf*)ws;                                   // 16 MiB (reused as attn_out)
  hbf*   Wt    = (hbf*)(ws + 16777216);                      // 6 MiB
  hbf*   Wpt   = (hbf*)(ws + 16777216 + 6291456);            // 2 MiB
  float* biasc = (float*)(ws + 16777216 + 6291456 + 2097152);// 12 KiB (+pad)
  hbf*   qkv   = (hbf*)(ws + 16777216 + 6291456 + 2097152 + 16384); // 48 MiB
  hbf*   attn  = xb;

  k_cvt_x_bias<<<8204, 256, 0, stream>>>(x, bq, bk, bv, xb, biasc);
  k_cvt_wqkv  <<<768,  256, 0, stream>>>(Wq, Wk, Wv, Wt);
  k_cvt_wp    <<<256,  256, 0, stream>>>(Wp, Wpt);

  dim3 g1(64, 12); k_gemm_qkv<<<g1, 512, 0, stream>>>(xb, Wt, biasc, qkv);
  dim3 g2(32, 16); k_flash   <<<g2, 512, 0, stream>>>(qkv, attn);
  dim3 g3(64, 4);  k_gemm_out<<<g3, 512, 0, stream>>>(attn, Wpt, bp, out);
}

// Round 18
// 198.400 us; speedup vs baseline: 1.1353x; 1.0027x over previous
//
#include <hip/hip_runtime.h>
#include <hip/hip_bf16.h>
#include <stdint.h>

// B=2, T=4096, D=1024, H=16, HS=64. Pipeline:
// fused cvt (x+bias; Wqkv/Wp LDS-transpose) -> GEMM qkv (8-phase 128x256;
// V TRANSPOSED [bh][e][t]) -> flash attn (Q-tile 256, 8 waves, 32x32 swapped
// MFMA, in-reg softmax, cvt_pk+permlane32_swap, defer-rescale, 4-deep LDS
// buffers w/ barrier per 2 tiles) -> GEMM out (8-phase, fp32 out).

typedef __bf16 bf16x8 __attribute__((ext_vector_type(8)));
typedef unsigned short ushort8v __attribute__((ext_vector_type(8)));
typedef float f32x4 __attribute__((ext_vector_type(4)));
typedef float f32x16 __attribute__((ext_vector_type(16)));
typedef __attribute__((address_space(1))) void gvoid_t;
typedef __attribute__((address_space(3))) void lvoid_t;

using hbf = __hip_bfloat16;

#define QSCALE (0.125f * 1.44269504088896f)  // 1/sqrt(HS) * log2(e)

static __device__ __forceinline__ void gload_lds16(const void* g, void* l) {
  __builtin_amdgcn_global_load_lds((gvoid_t*)g, (lvoid_t*)l, 16, 0, 0);
}

static __device__ __forceinline__ uint16_t b2u(float x) {
  hbf h = __float2bfloat16(x);
  return *reinterpret_cast<uint16_t*>(&h);
}

static __device__ __forceinline__ uint32_t cvtpk(float lo, float hi) {
  uint32_t r;
  asm("v_cvt_pk_bf16_f32 %0, %1, %2" : "=v"(r) : "v"(lo), "v"(hi));
  return r;
}

// v_permlane32_swap_b32: newX = {X.lo31 | Y.lo31->hi}, newY = {X.hi31->lo | Y.hi31}
static __device__ __forceinline__ void pl32swap(uint32_t& x, uint32_t& y) {
  asm volatile("v_permlane32_swap_b32 %0, %1" : "+v"(x), "+v"(y));
}

static __device__ __forceinline__ float max3f(float a, float b, float c) {
  return fmaxf(fmaxf(a, b), c);  // fuses to v_max3_f32
}

// ---------------- fused converters ----------------
// blocks [0,8192): x->xb ; [8192,8204): biases ; [8204,8972): Wqkv transpose ;
// [8972,9228): Wp transpose.

__global__ void k_cvt_all(const float* __restrict__ x,
                          const float* __restrict__ Wq, const float* __restrict__ Wk,
                          const float* __restrict__ Wv,
                          const float* __restrict__ bq, const float* __restrict__ bk,
                          const float* __restrict__ bv,
                          const float* __restrict__ Wp,
                          hbf* __restrict__ xb, hbf* __restrict__ Wt,
                          hbf* __restrict__ Wpt, float* __restrict__ biasc) {
  __shared__ float lds[64][65];
  const int b = blockIdx.x, tid = threadIdx.x;
  if (b < 8192) {
    int i = (b * 256 + tid) * 4;
    float4 v = *reinterpret_cast<const float4*>(x + i);
    hbf h[4] = {__float2bfloat16(v.x), __float2bfloat16(v.y),
                __float2bfloat16(v.z), __float2bfloat16(v.w)};
    *reinterpret_cast<ushort4*>(xb + i) = *reinterpret_cast<ushort4*>(h);
  } else if (b < 8204) {
    int r = (b - 8192) * 256 + tid;     // 0..3071
    int m = r >> 10, rem = r & 1023;
    const float* bsrc = (m == 0) ? bq : (m == 1) ? bk : bv;
    float v = bsrc[rem];
    if (m == 0) v *= QSCALE;
    biasc[r] = v;
  } else if (b < 8972) {
    const int bb = b - 8204;            // 0..767
    const int m = bb >> 8, h = (bb >> 4) & 15, d0 = (bb & 15) * 64;
    const float* W = (m == 0) ? Wq : (m == 1) ? Wk : Wv;
    const int dr = tid >> 4, ec = (tid & 15) * 4;
#pragma unroll
    for (int p = 0; p < 4; ++p) {
      const int row = p * 16 + dr;
      float4 v = *reinterpret_cast<const float4*>(
          W + ((size_t)((h << 10) + d0 + row)) * 64 + ec);
      if (m == 0) { v.x *= QSCALE; v.y *= QSCALE; v.z *= QSCALE; v.w *= QSCALE; }
      lds[row][ec] = v.x; lds[row][ec + 1] = v.y;
      lds[row][ec + 2] = v.z; lds[row][ec + 3] = v.w;
    }
    __syncthreads();
    const int e = tid >> 2, dj = (tid & 3) * 16;
    uint16_t tmp[16];
#pragma unroll
    for (int j = 0; j < 16; ++j) tmp[j] = b2u(lds[dj + j][e]);
    hbf* dst = Wt + ((size_t)(m * 1024 + (h << 6) + e)) * 1024 + d0 + dj;
    *reinterpret_cast<ushort8v*>(dst) = *reinterpret_cast<ushort8v*>(tmp);
    *reinterpret_cast<ushort8v*>(dst + 8) = *reinterpret_cast<ushort8v*>(tmp + 8);
  } else {
    const int bb = b - 8972;            // 0..255
    const int d0 = (bb >> 4) * 64, o0 = (bb & 15) * 64;
    const int dr = tid >> 4, oc = (tid & 15) * 4;
#pragma unroll
    for (int p = 0; p < 4; ++p) {
      const int row = p * 16 + dr;
      float4 v = *reinterpret_cast<const float4*>(Wp + (size_t)(d0 + row) * 1024 + o0 + oc);
      lds[row][oc] = v.x; lds[row][oc + 1] = v.y;
      lds[row][oc + 2] = v.z; lds[row][oc + 3] = v.w;
    }
    __syncthreads();
    const int ol = tid >> 2, dj = (tid & 3) * 16;
    uint16_t tmp[16];
#pragma unroll
    for (int j = 0; j < 16; ++j) tmp[j] = b2u(lds[dj + j][ol]);
    hbf* dst = Wpt + (size_t)(o0 + ol) * 1024 + d0 + dj;
    *reinterpret_cast<ushort8v*>(dst) = *reinterpret_cast<ushort8v*>(tmp);
    *reinterpret_cast<ushort8v*>(dst + 8) = *reinterpret_cast<ushort8v*>(tmp + 8);
  }
}

// ---------------- QKV projection GEMM (8-phase, R12-verified) ----------------

__global__ __launch_bounds__(512) void k_gemm_qkv(
    const hbf* __restrict__ A, const hbf* __restrict__ Bw,
    const float* __restrict__ biasc, hbf* __restrict__ qkv) {
  __shared__ __align__(16) hbf sA[2][128 * 64];
  __shared__ __align__(16) hbf sB[2][256 * 64];
  const int tid = threadIdx.x;
  const int lane = tid & 63, w = tid >> 6;
  const int wm = w >> 2, wn = w & 3;
  const int g = lane >> 4, cl = lane & 15;
  const int m0 = blockIdx.x * 128, n0 = blockIdx.y * 256;
  const int sr = tid >> 3, sc = tid & 7;

  const f32x4 fz = {0.f, 0.f, 0.f, 0.f};
  f32x4 acc[4][4];
#pragma unroll
  for (int a = 0; a < 4; ++a)
#pragma unroll
    for (int b = 0; b < 4; ++b) acc[a][b] = fz;

#pragma unroll
  for (int kt = 0; kt < 2; ++kt) {
#pragma unroll
    for (int s = 0; s < 2; ++s) {
      const int row = s * 64 + sr;
      gload_lds16(A + (size_t)(m0 + row) * 1024 + kt * 64 + ((sc ^ (row & 7)) * 8),
                  &sA[kt][s * 4096 + tid * 8]);
    }
#pragma unroll
    for (int s = 0; s < 4; ++s) {
      const int row = s * 64 + sr;
      gload_lds16(Bw + (size_t)(n0 + row) * 1024 + kt * 64 + ((sc ^ (row & 7)) * 8),
                  &sB[kt][s * 4096 + tid * 8]);
    }
  }
  asm volatile("s_waitcnt vmcnt(6)" ::: "memory");
  __builtin_amdgcn_s_barrier();

  for (int kt = 0; kt < 16; ++kt) {
    const int bi = kt & 1;
    const bool st = (kt + 2) < 16;

    bf16x8 af[4][2], bf[4][2];
#pragma unroll
    for (int rt = 0; rt < 4; ++rt)
#pragma unroll
      for (int ks = 0; ks < 2; ++ks)
        af[rt][ks] = *reinterpret_cast<const bf16x8*>(
            &sA[bi][(wm * 64 + rt * 16 + cl) * 64 + (((ks * 4 + g) ^ (cl & 7)) * 8)]);
#pragma unroll
    for (int ct = 0; ct < 4; ++ct)
#pragma unroll
      for (int ks = 0; ks < 2; ++ks)
        bf[ct][ks] = *reinterpret_cast<const bf16x8*>(
            &sB[bi][(wn * 64 + ct * 16 + cl) * 64 + (((ks * 4 + g) ^ (cl & 7)) * 8)]);
    __builtin_amdgcn_s_barrier();
    asm volatile("s_waitcnt lgkmcnt(0)" ::: "memory");
    __builtin_amdgcn_sched_barrier(0);
    __builtin_amdgcn_s_setprio(1);
#pragma unroll
    for (int rt = 0; rt < 4; ++rt)
#pragma unroll
      for (int ks = 0; ks < 2; ++ks)
        acc[rt][0] = __builtin_amdgcn_mfma_f32_16x16x32_bf16(af[rt][ks], bf[0][ks], acc[rt][0], 0, 0, 0);
    __builtin_amdgcn_s_setprio(0);
    __builtin_amdgcn_s_barrier();

#pragma unroll
    for (int q = 1; q < 4; ++q) {
      if (st) {
        if (q == 1) {
#pragma unroll
          for (int s = 0; s < 2; ++s) {
            const int row = s * 64 + sr;
            gload_lds16(A + (size_t)(m0 + row) * 1024 + (kt + 2) * 64 + ((sc ^ (row & 7)) * 8),
                        &sA[bi][s * 4096 + tid * 8]);
          }
        } else {
#pragma unroll
          for (int s2 = 0; s2 < 2; ++s2) {
            const int s = (q - 2) * 2 + s2;
            const int row = s * 64 + sr;
            gload_lds16(Bw + (size_t)(n0 + row) * 1024 + (kt + 2) * 64 + ((sc ^ (row & 7)) * 8),
                        &sB[bi][s * 4096 + tid * 8]);
          }
        }
      }
      __builtin_amdgcn_s_setprio(1);
#pragma unroll
      for (int rt = 0; rt < 4; ++rt)
#pragma unroll
        for (int ks = 0; ks < 2; ++ks)
          acc[rt][q] = __builtin_amdgcn_mfma_f32_16x16x32_bf16(af[rt][ks], bf[q][ks], acc[rt][q], 0, 0, 0);
      __builtin_amdgcn_s_setprio(0);
      if (q == 3) {
        if (st) asm volatile("s_waitcnt vmcnt(6)" ::: "memory");
        else    asm volatile("s_waitcnt vmcnt(0)" ::: "memory");
      }
      __builtin_amdgcn_s_barrier();
    }
  }

#pragma unroll
  for (int rt = 0; rt < 4; ++rt)
#pragma unroll
    for (int ct = 0; ct < 4; ++ct) {
      const int colg = n0 + wn * 64 + ct * 16 + cl;
      const int mi = colg >> 10, rem = colg & 1023;
      const int h = rem >> 6, e = rem & 63;
      const float bi_ = biasc[colg];
      if (mi == 2) {
        const int t0 = m0 + wm * 64 + rt * 16 + g * 4;
        const int b = t0 >> 12, t = t0 & 4095;
        ushort4 o;
        o.x = b2u(acc[rt][ct][0] + bi_);
        o.y = b2u(acc[rt][ct][1] + bi_);
        o.z = b2u(acc[rt][ct][2] + bi_);
        o.w = b2u(acc[rt][ct][3] + bi_);
        *reinterpret_cast<ushort4*>(
            qkv + (size_t)64 * 262144 + (size_t)(b * 16 + h) * 262144 + (size_t)e * 4096 + t) = o;
      } else {
#pragma unroll
        for (int i = 0; i < 4; ++i) {
          const int rowg = m0 + wm * 64 + rt * 16 + g * 4 + i;
          const int b = rowg >> 12, t = rowg & 4095;
          qkv[(((size_t)mi * 32 + b * 16 + h) * 4096 + t) * 64 + e] =
              __float2bfloat16(acc[rt][ct][i] + bi_);
        }
      }
    }
}

// ---------------- flash attention (Q-tile 256, 4-deep buffers) ----------------
// grid (bh=32, 16); qtb = y<8 ? 15-y : y-8. ntile = 4*qtb+4 (even).
// Super-iteration: process tiles 2s,2s+1; prefetch 2s+2,2s+3; ONE barrier.
// 4-deep K/V buffers (64KB LDS) let waves drift +-1 tile -> de-convoys the
// QK/softmax/PV phases across waves. Per-tile body is R13-verified.

__global__ __launch_bounds__(512) void k_flash(
    const hbf* __restrict__ qkv, hbf* __restrict__ attn) {
  __shared__ __align__(16) __bf16 sK[4][64 * 64];
  __shared__ __align__(16) __bf16 sV[4][64 * 64];
  const int tid = threadIdx.x, lane = tid & 63, wq = tid >> 6;  // wq in [0,8)
  const int h = lane >> 5, r31 = lane & 31;
  const int bh = blockIdx.x;
  const int y = (int)blockIdx.y;
  const int qtb = (y < 8) ? (15 - y) : (y - 8);   // 0..15
  const int q0 = qtb * 256;
  const int ntile = 4 * qtb + 4;
  const hbf* Q  = qkv + (size_t)bh * 262144;
  const hbf* Kp = qkv + (size_t)(32 + bh) * 262144;
  const hbf* Vp = qkv + (size_t)(64 + bh) * 262144;  // [e=64][t=4096]
  const float NEG_INF = -__builtin_inff();

  const int sr = tid >> 3, sc = tid & 7;
  const int koff = sr * 64 + ((sc ^ (sr & 7)) * 8);
  const int voff = sr * 4096 + ((sc ^ (sr & 7)) * 8);

  const int qrow = q0 + wq * 32 + r31;
  bf16x8 aq[4];
#pragma unroll
  for (int ks = 0; ks < 4; ++ks)
    aq[ks] = *reinterpret_cast<const bf16x8*>(Q + (size_t)qrow * 64 + ks * 16 + h * 8);

  f32x16 accO[2];
#pragma unroll
  for (int et = 0; et < 2; ++et)
#pragma unroll
    for (int i = 0; i < 16; ++i) accO[et][i] = 0.f;
  float mrow = NEG_INF, lrow = 0.f;

  // prologue: stage tiles 0,1 into bufs 0,1
  gload_lds16(Kp + koff,        &sK[0][tid * 8]);
  gload_lds16(Vp + voff,        &sV[0][tid * 8]);
  gload_lds16(Kp + 4096 + koff, &sK[1][tid * 8]);
  gload_lds16(Vp + 64 + voff,   &sV[1][tid * 8]);
  __syncthreads();

  const int qmaxw = q0 + wq * 32 + 31;
  const int nsuper = ntile >> 1;
  for (int s = 0; s < nsuper; ++s) {
    const int jt0 = 2 * s;
    // prefetch tiles jt0+2, jt0+3 (bufs freed by last super-iter's barrier)
    if (jt0 + 2 < ntile) {
      gload_lds16(Kp + (size_t)(jt0 + 2) * 4096 + koff, &sK[(jt0 + 2) & 3][tid * 8]);
      gload_lds16(Vp + (jt0 + 2) * 64 + voff,           &sV[(jt0 + 2) & 3][tid * 8]);
      gload_lds16(Kp + (size_t)(jt0 + 3) * 4096 + koff, &sK[(jt0 + 3) & 3][tid * 8]);
      gload_lds16(Vp + (jt0 + 3) * 64 + voff,           &sV[(jt0 + 3) & 3][tid * 8]);
    }

#pragma unroll
    for (int sub = 0; sub < 2; ++sub) {
      const int jt = jt0 + sub;
      if (64 * jt > qmaxw) break;  // later tiles in this super are also masked
      const __bf16* sKb = sK[jt & 3];
      const __bf16* sVb = sV[jt & 3];

      f32x16 accS[2];
      __builtin_amdgcn_s_setprio(1);
#pragma unroll
      for (int t = 0; t < 2; ++t) {
        f32x16 sacc;
#pragma unroll
        for (int i = 0; i < 16; ++i) sacc[i] = 0.f;
#pragma unroll
        for (int ks = 0; ks < 4; ++ks) {
          bf16x8 ak = *reinterpret_cast<const bf16x8*>(
              sKb + (t * 32 + r31) * 64 + (((2 * ks + h) ^ (r31 & 7)) * 8));
          sacc = __builtin_amdgcn_mfma_f32_32x32x16_bf16(ak, aq[ks], sacc, 0, 0, 0);
        }
        accS[t] = sacc;
      }
      __builtin_amdgcn_s_setprio(0);

      if (64 * jt + 63 > q0 + wq * 32) {  // diagonal region: mask kv > q
#pragma unroll
        for (int t = 0; t < 2; ++t)
#pragma unroll
          for (int i = 0; i < 16; ++i) {
            const int kvg = 64 * jt + 32 * t + (i & 3) + 8 * (i >> 2) + 4 * h;
            if (kvg > qrow) accS[t][i] = NEG_INF;
          }
      }

      float g0 = max3f(accS[0][0], accS[0][1], accS[0][2]);
      float g1 = max3f(accS[0][3], accS[0][4], accS[0][5]);
      float g2 = max3f(accS[0][6], accS[0][7], accS[0][8]);
      float g3 = max3f(accS[0][9], accS[0][10], accS[0][11]);
      float g4 = max3f(accS[0][12], accS[0][13], accS[0][14]);
      float g5 = max3f(accS[0][15], accS[1][0], accS[1][1]);
      float g6 = max3f(accS[1][2], accS[1][3], accS[1][4]);
      float g7 = max3f(accS[1][5], accS[1][6], accS[1][7]);
      float g8 = max3f(accS[1][8], accS[1][9], accS[1][10]);
      float g9 = max3f(accS[1][11], accS[1][12], accS[1][13]);
      float gA = fmaxf(accS[1][14], accS[1][15]);
      float h0 = max3f(g0, g1, g2);
      float h1 = max3f(g3, g4, g5);
      float h2 = max3f(g6, g7, g8);
      float h3 = fmaxf(g9, gA);
      float pmax = fmaxf(max3f(h0, h1, h2), h3);
      pmax = fmaxf(pmax, __shfl_xor(pmax, 32));

      if (!__all(pmax - mrow <= 8.f)) {  // defer-rescale (T13)
        const float mn = fmaxf(mrow, pmax);
        const float corr = __builtin_amdgcn_exp2f(mrow - mn);
        mrow = mn;
        lrow *= corr;
#pragma unroll
        for (int et = 0; et < 2; ++et)
#pragma unroll
          for (int i = 0; i < 16; ++i) accO[et][i] *= corr;
      }

#pragma unroll
      for (int t = 0; t < 2; ++t)
#pragma unroll
        for (int i = 0; i < 16; ++i)
          accS[t][i] = __builtin_amdgcn_exp2f(accS[t][i] - mrow);
      float s0 = (accS[0][0] + accS[0][1]) + (accS[0][2] + accS[0][3]);
      float s1 = (accS[0][4] + accS[0][5]) + (accS[0][6] + accS[0][7]);
      float s2 = (accS[0][8] + accS[0][9]) + (accS[0][10] + accS[0][11]);
      float s3 = (accS[0][12] + accS[0][13]) + (accS[0][14] + accS[0][15]);
      float s4 = (accS[1][0] + accS[1][1]) + (accS[1][2] + accS[1][3]);
      float s5 = (accS[1][4] + accS[1][5]) + (accS[1][6] + accS[1][7]);
      float s6 = (accS[1][8] + accS[1][9]) + (accS[1][10] + accS[1][11]);
      float s7 = (accS[1][12] + accS[1][13]) + (accS[1][14] + accS[1][15]);
      float rs = ((s0 + s1) + (s2 + s3)) + ((s4 + s5) + (s6 + s7));
      rs += __shfl_xor(rs, 32);
      lrow += rs;

      uint32_t d0[2][4], d1[2][4];
#pragma unroll
      for (int t = 0; t < 2; ++t)
#pragma unroll
        for (int r4 = 0; r4 < 4; ++r4) {
          d0[t][r4] = cvtpk(accS[t][4 * r4 + 0], accS[t][4 * r4 + 1]);
          d1[t][r4] = cvtpk(accS[t][4 * r4 + 2], accS[t][4 * r4 + 3]);
        }

#pragma unroll
      for (int kb = 0; kb < 4; ++kb) {
        const int t = kb >> 1, ra = 2 * (kb & 1), rb = ra + 1;
        uint32_t x0 = d0[t][ra], y0 = d0[t][rb];
        uint32_t x1 = d1[t][ra], y1 = d1[t][rb];
        pl32swap(x0, y0);
        pl32swap(x1, y1);
        union { uint32_t u[4]; bf16x8 v; } bP;
        bP.u[0] = x0; bP.u[1] = x1; bP.u[2] = y0; bP.u[3] = y1;
        __builtin_amdgcn_s_setprio(1);
#pragma unroll
        for (int et = 0; et < 2; ++et) {
          bf16x8 av = *reinterpret_cast<const bf16x8*>(
              sVb + (et * 32 + r31) * 64 + (((2 * kb + h) ^ (r31 & 7)) * 8));
          accO[et] = __builtin_amdgcn_mfma_f32_32x32x16_bf16(av, bP.v, accO[et], 0, 0, 0);
        }
        __builtin_amdgcn_s_setprio(0);
      }
    }

    __syncthreads();  // drains prefetch DMA; all waves done with bufs jt0,jt0+1
  }

  const float inv = 1.0f / lrow;
  hbf* arow = attn + ((size_t)(bh >> 4) * 4096 + qrow) * 1024 + (bh & 15) * 64;
#pragma unroll
  for (int et = 0; et < 2; ++et)
#pragma unroll
    for (int r4 = 0; r4 < 4; ++r4) {
      const int e0 = et * 32 + 8 * r4 + 4 * h;
      ushort4 o;
      o.x = b2u(accO[et][4 * r4 + 0] * inv);
      o.y = b2u(accO[et][4 * r4 + 1] * inv);
      o.z = b2u(accO[et][4 * r4 + 2] * inv);
      o.w = b2u(accO[et][4 * r4 + 3] * inv);
      *reinterpret_cast<ushort4*>(arow + e0) = o;
    }
}

// ---------------- output projection GEMM (8-phase 128x256, fp32 out) ----------------

__global__ __launch_bounds__(512) void k_gemm_out(
    const hbf* __restrict__ A, const hbf* __restrict__ Bw,
    const float* __restrict__ bp, float* __restrict__ out) {
  __shared__ __align__(16) hbf sA[2][128 * 64];
  __shared__ __align__(16) hbf sB[2][256 * 64];
  const int tid = threadIdx.x;
  const int lane = tid & 63, w = tid >> 6;
  const int wm = w >> 2, wn = w & 3;
  const int g = lane >> 4, cl = lane & 15;
  const int m0 = blockIdx.x * 128, n0 = blockIdx.y * 256;
  const int sr = tid >> 3, sc = tid & 7;

  const f32x4 fz = {0.f, 0.f, 0.f, 0.f};
  f32x4 acc[4][4];
#pragma unroll
  for (int a = 0; a < 4; ++a)
#pragma unroll
    for (int b = 0; b < 4; ++b) acc[a][b] = fz;

#pragma unroll
  for (int kt = 0; kt < 2; ++kt) {
#pragma unroll
    for (int s = 0; s < 2; ++s) {
      const int row = s * 64 + sr;
      gload_lds16(A + (size_t)(m0 + row) * 1024 + kt * 64 + ((sc ^ (row & 7)) * 8),
                  &sA[kt][s * 4096 + tid * 8]);
    }
#pragma unroll
    for (int s = 0; s < 4; ++s) {
      const int row = s * 64 + sr;
      gload_lds16(Bw + (size_t)(n0 + row) * 1024 + kt * 64 + ((sc ^ (row & 7)) * 8),
                  &sB[kt][s * 4096 + tid * 8]);
    }
  }
  asm volatile("s_waitcnt vmcnt(6)" ::: "memory");
  __builtin_amdgcn_s_barrier();

  for (int kt = 0; kt < 16; ++kt) {
    const int bi = kt & 1;
    const bool st = (kt + 2) < 16;

    bf16x8 af[4][2], bf[4][2];
#pragma unroll
    for (int rt = 0; rt < 4; ++rt)
#pragma unroll
      for (int ks = 0; ks < 2; ++ks)
        af[rt][ks] = *reinterpret_cast<const bf16x8*>(
            &sA[bi][(wm * 64 + rt * 16 + cl) * 64 + (((ks * 4 + g) ^ (cl & 7)) * 8)]);
#pragma unroll
    for (int ct = 0; ct < 4; ++ct)
#pragma unroll
      for (int ks = 0; ks < 2; ++ks)
        bf[ct][ks] = *reinterpret_cast<const bf16x8*>(
            &sB[bi][(wn * 64 + ct * 16 + cl) * 64 + (((ks * 4 + g) ^ (cl & 7)) * 8)]);
    __builtin_amdgcn_s_barrier();
    asm volatile("s_waitcnt lgkmcnt(0)" ::: "memory");
    __builtin_amdgcn_sched_barrier(0);
    __builtin_amdgcn_s_setprio(1);
#pragma unroll
    for (int rt = 0; rt < 4; ++rt)
#pragma unroll
      for (int ks = 0; ks < 2; ++ks)
        acc[rt][0] = __builtin_amdgcn_mfma_f32_16x16x32_bf16(af[rt][ks], bf[0][ks], acc[rt][0], 0, 0, 0);
    __builtin_amdgcn_s_setprio(0);
    __builtin_amdgcn_s_barrier();

#pragma unroll
    for (int q = 1; q < 4; ++q) {
      if (st) {
        if (q == 1) {
#pragma unroll
          for (int s = 0; s < 2; ++s) {
            const int row = s * 64 + sr;
            gload_lds16(A + (size_t)(m0 + row) * 1024 + (kt + 2) * 64 + ((sc ^ (row & 7)) * 8),
                        &sA[bi][s * 4096 + tid * 8]);
          }
        } else {
#pragma unroll
          for (int s2 = 0; s2 < 2; ++s2) {
            const int s = (q - 2) * 2 + s2;
            const int row = s * 64 + sr;
            gload_lds16(Bw + (size_t)(n0 + row) * 1024 + (kt + 2) * 64 + ((sc ^ (row & 7)) * 8),
                        &sB[bi][s * 4096 + tid * 8]);
          }
        }
      }
      __builtin_amdgcn_s_setprio(1);
#pragma unroll
      for (int rt = 0; rt < 4; ++rt)
#pragma unroll
        for (int ks = 0; ks < 2; ++ks)
          acc[rt][q] = __builtin_amdgcn_mfma_f32_16x16x32_bf16(af[rt][ks], bf[q][ks], acc[rt][q], 0, 0, 0);
      __builtin_amdgcn_s_setprio(0);
      if (q == 3) {
        if (st) asm volatile("s_waitcnt vmcnt(6)" ::: "memory");
        else    asm volatile("s_waitcnt vmcnt(0)" ::: "memory");
      }
      __builtin_amdgcn_s_barrier();
    }
  }

#pragma unroll
  for (int rt = 0; rt < 4; ++rt)
#pragma unroll
    for (int ct = 0; ct < 4; ++ct) {
      const int colg = n0 + wn * 64 + ct * 16 + cl;
      const float bi_ = bp[colg];
#pragma unroll
      for (int i = 0; i < 4; ++i) {
        const int rowg = m0 + wm * 64 + rt * 16 + g * 4 + i;
        out[(size_t)rowg * 1024 + colg] = acc[rt][ct][i] + bi_;
      }
    }
}

// ---------------- launcher ----------------

extern "C" void kernel_launch(void* const* d_in, const int* in_sizes, int n_in,
                              void* d_out, int out_size, void* d_ws, size_t ws_size,
                              hipStream_t stream) {
  const float* x  = (const float*)d_in[0];
  const float* Wq = (const float*)d_in[1];
  const float* Wk = (const float*)d_in[2];
  const float* Wv = (const float*)d_in[3];
  const float* bq = (const float*)d_in[4];
  const float* bk = (const float*)d_in[5];
  const float* bv = (const float*)d_in[6];
  const float* Wp = (const float*)d_in[7];
  const float* bp = (const float*)d_in[8];
  float* out = (float*)d_out;

  char* ws = (char*)d_ws;
  hbf*   xb    = (hbf*)ws;                                   // 16 MiB (reused as attn_out)
  hbf*   Wt    = (hbf*)(ws + 16777216);                      // 6 MiB
  hbf*   Wpt   = (hbf*)(ws + 16777216 + 6291456);            // 2 MiB
  float* biasc = (float*)(ws + 16777216 + 6291456 + 2097152);// 12 KiB (+pad)
  hbf*   qkv   = (hbf*)(ws + 16777216 + 6291456 + 2097152 + 16384); // 48 MiB
  hbf*   attn  = xb;

  k_cvt_all<<<9228, 256, 0, stream>>>(x, Wq, Wk, Wv, bq, bk, bv, Wp,
                                      xb, Wt, Wpt, biasc);

  dim3 g1(64, 12); k_gemm_qkv<<<g1, 512, 0, stream>>>(xb, Wt, biasc, qkv);
  dim3 g2(32, 16); k_flash   <<<g2, 512, 0, stream>>>(qkv, attn);
  dim3 g3(64, 4);  k_gemm_out<<<g3, 512, 0, stream>>>(attn, Wpt, bp, out);
}

// Round 19
// 195.861 us; speedup vs baseline: 1.1500x; 1.0130x over previous
//
#include <hip/hip_runtime.h>
#include <hip/hip_bf16.h>
#include <stdint.h>

// B=2, T=4096, D=1024, H=16, HS=64. Pipeline:
// fused cvt (x+bias; Wqkv/Wp LDS-transpose) -> GEMM qkv (8-phase 128x256;
// V TRANSPOSED [bh][e][t]) -> flash attn (Q-tile 256, 8 waves, 32x32 swapped
// MFMA, in-reg softmax, cvt_pk+permlane32_swap, defer-rescale, 2-deep dbuf
// swizzled K/V) -> GEMM out (8-phase, fp32 out).

typedef __bf16 bf16x8 __attribute__((ext_vector_type(8)));
typedef unsigned short ushort8v __attribute__((ext_vector_type(8)));
typedef float f32x4 __attribute__((ext_vector_type(4)));
typedef float f32x16 __attribute__((ext_vector_type(16)));
typedef __attribute__((address_space(1))) void gvoid_t;
typedef __attribute__((address_space(3))) void lvoid_t;

using hbf = __hip_bfloat16;

#define QSCALE (0.125f * 1.44269504088896f)  // 1/sqrt(HS) * log2(e)

static __device__ __forceinline__ void gload_lds16(const void* g, void* l) {
  __builtin_amdgcn_global_load_lds((gvoid_t*)g, (lvoid_t*)l, 16, 0, 0);
}

static __device__ __forceinline__ uint16_t b2u(float x) {
  hbf h = __float2bfloat16(x);
  return *reinterpret_cast<uint16_t*>(&h);
}

static __device__ __forceinline__ uint32_t cvtpk(float lo, float hi) {
  uint32_t r;
  asm("v_cvt_pk_bf16_f32 %0, %1, %2" : "=v"(r) : "v"(lo), "v"(hi));
  return r;
}

// v_permlane32_swap_b32: newX = {X.lo31 | Y.lo31->hi}, newY = {X.hi31->lo | Y.hi31}
static __device__ __forceinline__ void pl32swap(uint32_t& x, uint32_t& y) {
  asm volatile("v_permlane32_swap_b32 %0, %1" : "+v"(x), "+v"(y));
}

static __device__ __forceinline__ float max3f(float a, float b, float c) {
  return fmaxf(fmaxf(a, b), c);  // fuses to v_max3_f32
}

// ---------------- fused converters ----------------
// blocks [0,8192): x->xb ; [8192,8204): biases ; [8204,8972): Wqkv transpose ;
// [8972,9228): Wp transpose.

__global__ void k_cvt_all(const float* __restrict__ x,
                          const float* __restrict__ Wq, const float* __restrict__ Wk,
                          const float* __restrict__ Wv,
                          const float* __restrict__ bq, const float* __restrict__ bk,
                          const float* __restrict__ bv,
                          const float* __restrict__ Wp,
                          hbf* __restrict__ xb, hbf* __restrict__ Wt,
                          hbf* __restrict__ Wpt, float* __restrict__ biasc) {
  __shared__ float lds[64][65];
  const int b = blockIdx.x, tid = threadIdx.x;
  if (b < 8192) {
    int i = (b * 256 + tid) * 4;
    float4 v = *reinterpret_cast<const float4*>(x + i);
    hbf h[4] = {__float2bfloat16(v.x), __float2bfloat16(v.y),
                __float2bfloat16(v.z), __float2bfloat16(v.w)};
    *reinterpret_cast<ushort4*>(xb + i) = *reinterpret_cast<ushort4*>(h);
  } else if (b < 8204) {
    int r = (b - 8192) * 256 + tid;     // 0..3071
    int m = r >> 10, rem = r & 1023;
    const float* bsrc = (m == 0) ? bq : (m == 1) ? bk : bv;
    float v = bsrc[rem];
    if (m == 0) v *= QSCALE;
    biasc[r] = v;
  } else if (b < 8972) {
    const int bb = b - 8204;            // 0..767
    const int m = bb >> 8, h = (bb >> 4) & 15, d0 = (bb & 15) * 64;
    const float* W = (m == 0) ? Wq : (m == 1) ? Wk : Wv;
    const int dr = tid >> 4, ec = (tid & 15) * 4;
#pragma unroll
    for (int p = 0; p < 4; ++p) {
      const int row = p * 16 + dr;
      float4 v = *reinterpret_cast<const float4*>(
          W + ((size_t)((h << 10) + d0 + row)) * 64 + ec);
      if (m == 0) { v.x *= QSCALE; v.y *= QSCALE; v.z *= QSCALE; v.w *= QSCALE; }
      lds[row][ec] = v.x; lds[row][ec + 1] = v.y;
      lds[row][ec + 2] = v.z; lds[row][ec + 3] = v.w;
    }
    __syncthreads();
    const int e = tid >> 2, dj = (tid & 3) * 16;
    uint16_t tmp[16];
#pragma unroll
    for (int j = 0; j < 16; ++j) tmp[j] = b2u(lds[dj + j][e]);
    hbf* dst = Wt + ((size_t)(m * 1024 + (h << 6) + e)) * 1024 + d0 + dj;
    *reinterpret_cast<ushort8v*>(dst) = *reinterpret_cast<ushort8v*>(tmp);
    *reinterpret_cast<ushort8v*>(dst + 8) = *reinterpret_cast<ushort8v*>(tmp + 8);
  } else {
    const int bb = b - 8972;            // 0..255
    const int d0 = (bb >> 4) * 64, o0 = (bb & 15) * 64;
    const int dr = tid >> 4, oc = (tid & 15) * 4;
#pragma unroll
    for (int p = 0; p < 4; ++p) {
      const int row = p * 16 + dr;
      float4 v = *reinterpret_cast<const float4*>(Wp + (size_t)(d0 + row) * 1024 + o0 + oc);
      lds[row][oc] = v.x; lds[row][oc + 1] = v.y;
      lds[row][oc + 2] = v.z; lds[row][oc + 3] = v.w;
    }
    __syncthreads();
    const int ol = tid >> 2, dj = (tid & 3) * 16;
    uint16_t tmp[16];
#pragma unroll
    for (int j = 0; j < 16; ++j) tmp[j] = b2u(lds[dj + j][ol]);
    hbf* dst = Wpt + (size_t)(o0 + ol) * 1024 + d0 + dj;
    *reinterpret_cast<ushort8v*>(dst) = *reinterpret_cast<ushort8v*>(tmp);
    *reinterpret_cast<ushort8v*>(dst + 8) = *reinterpret_cast<ushort8v*>(tmp + 8);
  }
}

// ---------------- QKV projection GEMM (8-phase, R12-verified) ----------------

__global__ __launch_bounds__(512) void k_gemm_qkv(
    const hbf* __restrict__ A, const hbf* __restrict__ Bw,
    const float* __restrict__ biasc, hbf* __restrict__ qkv) {
  __shared__ __align__(16) hbf sA[2][128 * 64];
  __shared__ __align__(16) hbf sB[2][256 * 64];
  const int tid = threadIdx.x;
  const int lane = tid & 63, w = tid >> 6;
  const int wm = w >> 2, wn = w & 3;
  const int g = lane >> 4, cl = lane & 15;
  const int m0 = blockIdx.x * 128, n0 = blockIdx.y * 256;
  const int sr = tid >> 3, sc = tid & 7;

  const f32x4 fz = {0.f, 0.f, 0.f, 0.f};
  f32x4 acc[4][4];
#pragma unroll
  for (int a = 0; a < 4; ++a)
#pragma unroll
    for (int b = 0; b < 4; ++b) acc[a][b] = fz;

#pragma unroll
  for (int kt = 0; kt < 2; ++kt) {
#pragma unroll
    for (int s = 0; s < 2; ++s) {
      const int row = s * 64 + sr;
      gload_lds16(A + (size_t)(m0 + row) * 1024 + kt * 64 + ((sc ^ (row & 7)) * 8),
                  &sA[kt][s * 4096 + tid * 8]);
    }
#pragma unroll
    for (int s = 0; s < 4; ++s) {
      const int row = s * 64 + sr;
      gload_lds16(Bw + (size_t)(n0 + row) * 1024 + kt * 64 + ((sc ^ (row & 7)) * 8),
                  &sB[kt][s * 4096 + tid * 8]);
    }
  }
  asm volatile("s_waitcnt vmcnt(6)" ::: "memory");
  __builtin_amdgcn_s_barrier();

  for (int kt = 0; kt < 16; ++kt) {
    const int bi = kt & 1;
    const bool st = (kt + 2) < 16;

    bf16x8 af[4][2], bf[4][2];
#pragma unroll
    for (int rt = 0; rt < 4; ++rt)
#pragma unroll
      for (int ks = 0; ks < 2; ++ks)
        af[rt][ks] = *reinterpret_cast<const bf16x8*>(
            &sA[bi][(wm * 64 + rt * 16 + cl) * 64 + (((ks * 4 + g) ^ (cl & 7)) * 8)]);
#pragma unroll
    for (int ct = 0; ct < 4; ++ct)
#pragma unroll
      for (int ks = 0; ks < 2; ++ks)
        bf[ct][ks] = *reinterpret_cast<const bf16x8*>(
            &sB[bi][(wn * 64 + ct * 16 + cl) * 64 + (((ks * 4 + g) ^ (cl & 7)) * 8)]);
    __builtin_amdgcn_s_barrier();
    asm volatile("s_waitcnt lgkmcnt(0)" ::: "memory");
    __builtin_amdgcn_sched_barrier(0);
    __builtin_amdgcn_s_setprio(1);
#pragma unroll
    for (int rt = 0; rt < 4; ++rt)
#pragma unroll
      for (int ks = 0; ks < 2; ++ks)
        acc[rt][0] = __builtin_amdgcn_mfma_f32_16x16x32_bf16(af[rt][ks], bf[0][ks], acc[rt][0], 0, 0, 0);
    __builtin_amdgcn_s_setprio(0);
    __builtin_amdgcn_s_barrier();

#pragma unroll
    for (int q = 1; q < 4; ++q) {
      if (st) {
        if (q == 1) {
#pragma unroll
          for (int s = 0; s < 2; ++s) {
            const int row = s * 64 + sr;
            gload_lds16(A + (size_t)(m0 + row) * 1024 + (kt + 2) * 64 + ((sc ^ (row & 7)) * 8),
                        &sA[bi][s * 4096 + tid * 8]);
          }
        } else {
#pragma unroll
          for (int s2 = 0; s2 < 2; ++s2) {
            const int s = (q - 2) * 2 + s2;
            const int row = s * 64 + sr;
            gload_lds16(Bw + (size_t)(n0 + row) * 1024 + (kt + 2) * 64 + ((sc ^ (row & 7)) * 8),
                        &sB[bi][s * 4096 + tid * 8]);
          }
        }
      }
      __builtin_amdgcn_s_setprio(1);
#pragma unroll
      for (int rt = 0; rt < 4; ++rt)
#pragma unroll
        for (int ks = 0; ks < 2; ++ks)
          acc[rt][q] = __builtin_amdgcn_mfma_f32_16x16x32_bf16(af[rt][ks], bf[q][ks], acc[rt][q], 0, 0, 0);
      __builtin_amdgcn_s_setprio(0);
      if (q == 3) {
        if (st) asm volatile("s_waitcnt vmcnt(6)" ::: "memory");
        else    asm volatile("s_waitcnt vmcnt(0)" ::: "memory");
      }
      __builtin_amdgcn_s_barrier();
    }
  }

#pragma unroll
  for (int rt = 0; rt < 4; ++rt)
#pragma unroll
    for (int ct = 0; ct < 4; ++ct) {
      const int colg = n0 + wn * 64 + ct * 16 + cl;
      const int mi = colg >> 10, rem = colg & 1023;
      const int h = rem >> 6, e = rem & 63;
      const float bi_ = biasc[colg];
      if (mi == 2) {
        const int t0 = m0 + wm * 64 + rt * 16 + g * 4;
        const int b = t0 >> 12, t = t0 & 4095;
        ushort4 o;
        o.x = b2u(acc[rt][ct][0] + bi_);
        o.y = b2u(acc[rt][ct][1] + bi_);
        o.z = b2u(acc[rt][ct][2] + bi_);
        o.w = b2u(acc[rt][ct][3] + bi_);
        *reinterpret_cast<ushort4*>(
            qkv + (size_t)64 * 262144 + (size_t)(b * 16 + h) * 262144 + (size_t)e * 4096 + t) = o;
      } else {
#pragma unroll
        for (int i = 0; i < 4; ++i) {
          const int rowg = m0 + wm * 64 + rt * 16 + g * 4 + i;
          const int b = rowg >> 12, t = rowg & 4095;
          qkv[(((size_t)mi * 32 + b * 16 + h) * 4096 + t) * 64 + e] =
              __float2bfloat16(acc[rt][ct][i] + bi_);
        }
      }
    }
}

// ---------------- flash attention (R17-verified: Q-tile 256, 2-deep dbuf) ----------------
// grid (bh=32, 16); qtb = y<8 ? 15-y : y-8 (balanced 68-iter pairs per CU).
// 8 waves x 32 q-rows = 256 q; 512 threads stage 64x64 K/V tiles with ONE
// gload_lds16 each; one barrier per tile.

__global__ __launch_bounds__(512) void k_flash(
    const hbf* __restrict__ qkv, hbf* __restrict__ attn) {
  __shared__ __align__(16) __bf16 sK[2][64 * 64];
  __shared__ __align__(16) __bf16 sV[2][64 * 64];
  const int tid = threadIdx.x, lane = tid & 63, wq = tid >> 6;  // wq in [0,8)
  const int h = lane >> 5, r31 = lane & 31;
  const int bh = blockIdx.x;
  const int y = (int)blockIdx.y;
  const int qtb = (y < 8) ? (15 - y) : (y - 8);   // 0..15
  const int q0 = qtb * 256;
  const int ntile = 4 * qtb + 4;
  const hbf* Q  = qkv + (size_t)bh * 262144;
  const hbf* Kp = qkv + (size_t)(32 + bh) * 262144;
  const hbf* Vp = qkv + (size_t)(64 + bh) * 262144;  // [e=64][t=4096]
  const float NEG_INF = -__builtin_inff();

  const int sr = tid >> 3, sc = tid & 7;
  const int koff = sr * 64 + ((sc ^ (sr & 7)) * 8);        // K[t=row][e-chunk]
  const int voff = sr * 4096 + ((sc ^ (sr & 7)) * 8);      // V^T[e=row][t-chunk]

  const int qrow = q0 + wq * 32 + r31;
  bf16x8 aq[4];
#pragma unroll
  for (int ks = 0; ks < 4; ++ks)
    aq[ks] = *reinterpret_cast<const bf16x8*>(Q + (size_t)qrow * 64 + ks * 16 + h * 8);

  f32x16 accO[2];
#pragma unroll
  for (int et = 0; et < 2; ++et)
#pragma unroll
    for (int i = 0; i < 16; ++i) accO[et][i] = 0.f;
  float mrow = NEG_INF, lrow = 0.f;

  gload_lds16(Kp + koff, &sK[0][tid * 8]);
  gload_lds16(Vp + voff, &sV[0][tid * 8]);
  __syncthreads();

  const int qmaxw = q0 + wq * 32 + 31;
  int buf = 0;
  for (int jt = 0; jt < ntile; ++jt) {
    if (jt < ntile - 1) {  // prefetch next tile (pure DMA)
      gload_lds16(Kp + (size_t)(jt + 1) * 4096 + koff, &sK[buf ^ 1][tid * 8]);
      gload_lds16(Vp + (jt + 1) * 64 + voff,           &sV[buf ^ 1][tid * 8]);
    }

    if (64 * jt <= qmaxw) {  // wave has unmasked work in this tile
      const __bf16* sKb = sK[buf];
      const __bf16* sVb = sV[buf];

      f32x16 accS[2];
      __builtin_amdgcn_s_setprio(1);
#pragma unroll
      for (int t = 0; t < 2; ++t) {
        f32x16 s;
#pragma unroll
        for (int i = 0; i < 16; ++i) s[i] = 0.f;
#pragma unroll
        for (int ks = 0; ks < 4; ++ks) {
          bf16x8 ak = *reinterpret_cast<const bf16x8*>(
              sKb + (t * 32 + r31) * 64 + (((2 * ks + h) ^ (r31 & 7)) * 8));
          s = __builtin_amdgcn_mfma_f32_32x32x16_bf16(ak, aq[ks], s, 0, 0, 0);
        }
        accS[t] = s;
      }
      __builtin_amdgcn_s_setprio(0);

      if (64 * jt + 63 > q0 + wq * 32) {  // diagonal region: mask kv > q
#pragma unroll
        for (int t = 0; t < 2; ++t)
#pragma unroll
          for (int i = 0; i < 16; ++i) {
            const int kvg = 64 * jt + 32 * t + (i & 3) + 8 * (i >> 2) + 4 * h;
            if (kvg > qrow) accS[t][i] = NEG_INF;
          }
      }

      float g0 = max3f(accS[0][0], accS[0][1], accS[0][2]);
      float g1 = max3f(accS[0][3], accS[0][4], accS[0][5]);
      float g2 = max3f(accS[0][6], accS[0][7], accS[0][8]);
      float g3 = max3f(accS[0][9], accS[0][10], accS[0][11]);
      float g4 = max3f(accS[0][12], accS[0][13], accS[0][14]);
      float g5 = max3f(accS[0][15], accS[1][0], accS[1][1]);
      float g6 = max3f(accS[1][2], accS[1][3], accS[1][4]);
      float g7 = max3f(accS[1][5], accS[1][6], accS[1][7]);
      float g8 = max3f(accS[1][8], accS[1][9], accS[1][10]);
      float g9 = max3f(accS[1][11], accS[1][12], accS[1][13]);
      float gA = fmaxf(accS[1][14], accS[1][15]);
      float h0 = max3f(g0, g1, g2);
      float h1 = max3f(g3, g4, g5);
      float h2 = max3f(g6, g7, g8);
      float h3 = fmaxf(g9, gA);
      float pmax = fmaxf(max3f(h0, h1, h2), h3);
      pmax = fmaxf(pmax, __shfl_xor(pmax, 32));

      if (!__all(pmax - mrow <= 8.f)) {  // defer-rescale (T13)
        const float mn = fmaxf(mrow, pmax);
        const float corr = __builtin_amdgcn_exp2f(mrow - mn);
        mrow = mn;
        lrow *= corr;
#pragma unroll
        for (int et = 0; et < 2; ++et)
#pragma unroll
          for (int i = 0; i < 16; ++i) accO[et][i] *= corr;
      }

#pragma unroll
      for (int t = 0; t < 2; ++t)
#pragma unroll
        for (int i = 0; i < 16; ++i)
          accS[t][i] = __builtin_amdgcn_exp2f(accS[t][i] - mrow);
      float s0 = (accS[0][0] + accS[0][1]) + (accS[0][2] + accS[0][3]);
      float s1 = (accS[0][4] + accS[0][5]) + (accS[0][6] + accS[0][7]);
      float s2 = (accS[0][8] + accS[0][9]) + (accS[0][10] + accS[0][11]);
      float s3 = (accS[0][12] + accS[0][13]) + (accS[0][14] + accS[0][15]);
      float s4 = (accS[1][0] + accS[1][1]) + (accS[1][2] + accS[1][3]);
      float s5 = (accS[1][4] + accS[1][5]) + (accS[1][6] + accS[1][7]);
      float s6 = (accS[1][8] + accS[1][9]) + (accS[1][10] + accS[1][11]);
      float s7 = (accS[1][12] + accS[1][13]) + (accS[1][14] + accS[1][15]);
      float rs = ((s0 + s1) + (s2 + s3)) + ((s4 + s5) + (s6 + s7));
      rs += __shfl_xor(rs, 32);
      lrow += rs;

      uint32_t d0[2][4], d1[2][4];
#pragma unroll
      for (int t = 0; t < 2; ++t)
#pragma unroll
        for (int r4 = 0; r4 < 4; ++r4) {
          d0[t][r4] = cvtpk(accS[t][4 * r4 + 0], accS[t][4 * r4 + 1]);
          d1[t][r4] = cvtpk(accS[t][4 * r4 + 2], accS[t][4 * r4 + 3]);
        }

#pragma unroll
      for (int kb = 0; kb < 4; ++kb) {
        const int t = kb >> 1, ra = 2 * (kb & 1), rb = ra + 1;
        uint32_t x0 = d0[t][ra], y0 = d0[t][rb];
        uint32_t x1 = d1[t][ra], y1 = d1[t][rb];
        pl32swap(x0, y0);
        pl32swap(x1, y1);
        union { uint32_t u[4]; bf16x8 v; } bP;
        bP.u[0] = x0; bP.u[1] = x1; bP.u[2] = y0; bP.u[3] = y1;
        __builtin_amdgcn_s_setprio(1);
#pragma unroll
        for (int et = 0; et < 2; ++et) {
          bf16x8 av = *reinterpret_cast<const bf16x8*>(
              sVb + (et * 32 + r31) * 64 + (((2 * kb + h) ^ (r31 & 7)) * 8));
          accO[et] = __builtin_amdgcn_mfma_f32_32x32x16_bf16(av, bP.v, accO[et], 0, 0, 0);
        }
        __builtin_amdgcn_s_setprio(0);
      }
    }

    __syncthreads();
    buf ^= 1;
  }

  const float inv = 1.0f / lrow;
  hbf* arow = attn + ((size_t)(bh >> 4) * 4096 + qrow) * 1024 + (bh & 15) * 64;
#pragma unroll
  for (int et = 0; et < 2; ++et)
#pragma unroll
    for (int r4 = 0; r4 < 4; ++r4) {
      const int e0 = et * 32 + 8 * r4 + 4 * h;
      ushort4 o;
      o.x = b2u(accO[et][4 * r4 + 0] * inv);
      o.y = b2u(accO[et][4 * r4 + 1] * inv);
      o.z = b2u(accO[et][4 * r4 + 2] * inv);
      o.w = b2u(accO[et][4 * r4 + 3] * inv);
      *reinterpret_cast<ushort4*>(arow + e0) = o;
    }
}

// ---------------- output projection GEMM (8-phase 128x256, fp32 out) ----------------

__global__ __launch_bounds__(512) void k_gemm_out(
    const hbf* __restrict__ A, const hbf* __restrict__ Bw,
    const float* __restrict__ bp, float* __restrict__ out) {
  __shared__ __align__(16) hbf sA[2][128 * 64];
  __shared__ __align__(16) hbf sB[2][256 * 64];
  const int tid = threadIdx.x;
  const int lane = tid & 63, w = tid >> 6;
  const int wm = w >> 2, wn = w & 3;
  const int g = lane >> 4, cl = lane & 15;
  const int m0 = blockIdx.x * 128, n0 = blockIdx.y * 256;
  const int sr = tid >> 3, sc = tid & 7;

  const f32x4 fz = {0.f, 0.f, 0.f, 0.f};
  f32x4 acc[4][4];
#pragma unroll
  for (int a = 0; a < 4; ++a)
#pragma unroll
    for (int b = 0; b < 4; ++b) acc[a][b] = fz;

#pragma unroll
  for (int kt = 0; kt < 2; ++kt) {
#pragma unroll
    for (int s = 0; s < 2; ++s) {
      const int row = s * 64 + sr;
      gload_lds16(A + (size_t)(m0 + row) * 1024 + kt * 64 + ((sc ^ (row & 7)) * 8),
                  &sA[kt][s * 4096 + tid * 8]);
    }
#pragma unroll
    for (int s = 0; s < 4; ++s) {
      const int row = s * 64 + sr;
      gload_lds16(Bw + (size_t)(n0 + row) * 1024 + kt * 64 + ((sc ^ (row & 7)) * 8),
                  &sB[kt][s * 4096 + tid * 8]);
    }
  }
  asm volatile("s_waitcnt vmcnt(6)" ::: "memory");
  __builtin_amdgcn_s_barrier();

  for (int kt = 0; kt < 16; ++kt) {
    const int bi = kt & 1;
    const bool st = (kt + 2) < 16;

    bf16x8 af[4][2], bf[4][2];
#pragma unroll
    for (int rt = 0; rt < 4; ++rt)
#pragma unroll
      for (int ks = 0; ks < 2; ++ks)
        af[rt][ks] = *reinterpret_cast<const bf16x8*>(
            &sA[bi][(wm * 64 + rt * 16 + cl) * 64 + (((ks * 4 + g) ^ (cl & 7)) * 8)]);
#pragma unroll
    for (int ct = 0; ct < 4; ++ct)
#pragma unroll
      for (int ks = 0; ks < 2; ++ks)
        bf[ct][ks] = *reinterpret_cast<const bf16x8*>(
            &sB[bi][(wn * 64 + ct * 16 + cl) * 64 + (((ks * 4 + g) ^ (cl & 7)) * 8)]);
    __builtin_amdgcn_s_barrier();
    asm volatile("s_waitcnt lgkmcnt(0)" ::: "memory");
    __builtin_amdgcn_sched_barrier(0);
    __builtin_amdgcn_s_setprio(1);
#pragma unroll
    for (int rt = 0; rt < 4; ++rt)
#pragma unroll
      for (int ks = 0; ks < 2; ++ks)
        acc[rt][0] = __builtin_amdgcn_mfma_f32_16x16x32_bf16(af[rt][ks], bf[0][ks], acc[rt][0], 0, 0, 0);
    __builtin_amdgcn_s_setprio(0);
    __builtin_amdgcn_s_barrier();

#pragma unroll
    for (int q = 1; q < 4; ++q) {
      if (st) {
        if (q == 1) {
#pragma unroll
          for (int s = 0; s < 2; ++s) {
            const int row = s * 64 + sr;
            gload_lds16(A + (size_t)(m0 + row) * 1024 + (kt + 2) * 64 + ((sc ^ (row & 7)) * 8),
                        &sA[bi][s * 4096 + tid * 8]);
          }
        } else {
#pragma unroll
          for (int s2 = 0; s2 < 2; ++s2) {
            const int s = (q - 2) * 2 + s2;
            const int row = s * 64 + sr;
            gload_lds16(Bw + (size_t)(n0 + row) * 1024 + (kt + 2) * 64 + ((sc ^ (row & 7)) * 8),
                        &sB[bi][s * 4096 + tid * 8]);
          }
        }
      }
      __builtin_amdgcn_s_setprio(1);
#pragma unroll
      for (int rt = 0; rt < 4; ++rt)
#pragma unroll
        for (int ks = 0; ks < 2; ++ks)
          acc[rt][q] = __builtin_amdgcn_mfma_f32_16x16x32_bf16(af[rt][ks], bf[q][ks], acc[rt][q], 0, 0, 0);
      __builtin_amdgcn_s_setprio(0);
      if (q == 3) {
        if (st) asm volatile("s_waitcnt vmcnt(6)" ::: "memory");
        else    asm volatile("s_waitcnt vmcnt(0)" ::: "memory");
      }
      __builtin_amdgcn_s_barrier();
    }
  }

#pragma unroll
  for (int rt = 0; rt < 4; ++rt)
#pragma unroll
    for (int ct = 0; ct < 4; ++ct) {
      const int colg = n0 + wn * 64 + ct * 16 + cl;
      const float bi_ = bp[colg];
#pragma unroll
      for (int i = 0; i < 4; ++i) {
        const int rowg = m0 + wm * 64 + rt * 16 + g * 4 + i;
        out[(size_t)rowg * 1024 + colg] = acc[rt][ct][i] + bi_;
      }
    }
}

// ---------------- launcher ----------------

extern "C" void kernel_launch(void* const* d_in, const int* in_sizes, int n_in,
                              void* d_out, int out_size, void* d_ws, size_t ws_size,
                              hipStream_t stream) {
  const float* x  = (const float*)d_in[0];
  const float* Wq = (const float*)d_in[1];
  const float* Wk = (const float*)d_in[2];
  const float* Wv = (const float*)d_in[3];
  const float* bq = (const float*)d_in[4];
  const float* bk = (const float*)d_in[5];
  const float* bv = (const float*)d_in[6];
  const float* Wp = (const float*)d_in[7];
  const float* bp = (const float*)d_in[8];
  float* out = (float*)d_out;

  char* ws = (char*)d_ws;
  hbf*   xb    = (hbf*)ws;                                   // 16 MiB (reused as attn_out)
  hbf*   Wt    = (hbf*)(ws + 16777216);                      // 6 MiB
  hbf*   Wpt   = (hbf*)(ws + 16777216 + 6291456);            // 2 MiB
  float* biasc = (float*)(ws + 16777216 + 6291456 + 2097152);// 12 KiB (+pad)
  hbf*   qkv   = (hbf*)(ws + 16777216 + 6291456 + 2097152 + 16384); // 48 MiB
  hbf*   attn  = xb;

  k_cvt_all<<<9228, 256, 0, stream>>>(x, Wq, Wk, Wv, bq, bk, bv, Wp,
                                      xb, Wt, Wpt, biasc);

  dim3 g1(64, 12); k_gemm_qkv<<<g1, 512, 0, stream>>>(xb, Wt, biasc, qkv);
  dim3 g2(32, 16); k_flash   <<<g2, 512, 0, stream>>>(qkv, attn);
  dim3 g3(64, 4);  k_gemm_out<<<g3, 512, 0, stream>>>(attn, Wpt, bp, out);
}